// Round 1
// baseline (5418.431 us; speedup 1.0000x reference)
//
#include <hip/hip_runtime.h>
#include <math.h>

constexpr int NCL   = 64;
constexpr int NN    = 8;
constexpr int NG    = 4;            // batch elements per block
constexpr int NODES = NG * NN;      // 32
constexpr int NT    = 512;          // 8 waves

__device__ __forceinline__ float elu_f(float x) {
    return x > 0.0f ? x : (__expf(x) - 1.0f);
}
__device__ __forceinline__ float f4c(const float4 v, int k) {
    return k == 0 ? v.x : k == 1 ? v.y : k == 2 ? v.z : v.w;
}

__global__ __launch_bounds__(NT)
void gh_kernel(const float* __restrict__ S,
               const float* __restrict__ W_enc,  const float* __restrict__ b_enc,
               const float* __restrict__ W_self0,const float* __restrict__ b_self0,
               const float* __restrict__ W_self1,const float* __restrict__ b_self1,
               const float* __restrict__ W_rel0, const float* __restrict__ b_rel0,
               const float* __restrict__ W_rel1, const float* __restrict__ b_rel1,
               const float* __restrict__ W_rel2, const float* __restrict__ b_rel2,
               const float* __restrict__ W_att0, const float* __restrict__ b_att0,
               const float* __restrict__ W_att1, const float* __restrict__ b_att1,
               const float* __restrict__ W_att2, const float* __restrict__ b_att2,
               float* __restrict__ Out)
{
    // LDS budget: 66048 + 65536 + 16384 + 8192 + 256 + 1024 + 2048 = 159488 B (< 160 KiB)
    __shared__ __align__(16) float wbuf[129 * 128];      // staged weights (reused per phase)
    __shared__ __align__(16) float AB[4][NODES][128];    // 0:A_rel(+b) 1:B_rel 2:A_att(+b) 3:B_att
    __shared__ __align__(16) float sc[8][4][128];        // pair scratch; aliases s_raw / h
    __shared__ __align__(16) float encl[NODES][64];      // s after encoder-concat
    __shared__ float posl[NODES][2];
    __shared__ float attl[8][4][NN];                     // attention scalars per (wave,row,j)
    __shared__ float fin[8][64];

    const int tid  = threadIdx.x;
    const int w    = tid >> 6;
    const int lane = tid & 63;
    const int b0   = blockIdx.x * NG;
    const int nd0  = w * 4;                              // wave's first local node

    float* s_raw = &sc[0][0][0];                         // 2048 floats
    float* h_lds = s_raw + NODES * NCL;                  // 2048 floats

    // ---------------- load s + stage W_enc ----------------
    for (int idx = tid; idx < NODES * NCL; idx += NT)
        s_raw[idx] = S[(size_t)b0 * NN * NCL + idx];
    for (int idx = tid; idx < NCL * NCL; idx += NT)
        wbuf[idx] = W_enc[idx];
    __syncthreads();

    if (tid < NODES * 2)
        posl[tid >> 1][tid & 1] = s_raw[(tid >> 1) * NCL + (tid & 1)];

    // ---------------- encoder: s_enc = concat(s[:2], (s@W_enc+b)[2:]) ----------------
    {
        const float bias = b_enc[lane];
        float acc[4] = {bias, bias, bias, bias};
        for (int k = 0; k < NCL; k += 4) {
            float4 sb[4];
            #pragma unroll
            for (int r = 0; r < 4; ++r)
                sb[r] = *(const float4*)&s_raw[(nd0 + r) * NCL + k];
            #pragma unroll
            for (int kk = 0; kk < 4; ++kk) {
                const float wv = wbuf[(k + kk) * NCL + lane];
                #pragma unroll
                for (int r = 0; r < 4; ++r)
                    acc[r] = fmaf(f4c(sb[r], kk), wv, acc[r]);
            }
        }
        #pragma unroll
        for (int r = 0; r < 4; ++r)
            encl[nd0 + r][lane] = (lane < 2) ? s_raw[(nd0 + r) * NCL + lane] : acc[r];
    }
    __syncthreads();

    // ---------------- h = elu(s_enc @ W_self0 + b) ----------------
    for (int idx = tid; idx < NCL * NCL; idx += NT) wbuf[idx] = W_self0[idx];
    __syncthreads();
    float hreg[4];
    {
        const float bias = b_self0[lane];
        float acc[4] = {bias, bias, bias, bias};
        for (int k = 0; k < NCL; k += 4) {
            float4 sb[4];
            #pragma unroll
            for (int r = 0; r < 4; ++r)
                sb[r] = *(const float4*)&encl[nd0 + r][k];
            #pragma unroll
            for (int kk = 0; kk < 4; ++kk) {
                const float wv = wbuf[(k + kk) * NCL + lane];
                #pragma unroll
                for (int r = 0; r < 4; ++r)
                    acc[r] = fmaf(f4c(sb[r], kk), wv, acc[r]);
            }
        }
        #pragma unroll
        for (int r = 0; r < 4; ++r) {
            hreg[r] = elu_f(acc[r]);
            h_lds[(nd0 + r) * NCL + lane] = hreg[r];
        }
    }
    __syncthreads();

    // ---------------- self_dyn = h @ W_self1 + b + h  (summed over wave's 4 nodes) ----
    for (int idx = tid; idx < NCL * NCL; idx += NT) wbuf[idx] = W_self1[idx];
    __syncthreads();
    float ssum = 0.0f;
    {
        const float bias = b_self1[lane];
        float acc[4] = {bias, bias, bias, bias};
        for (int k = 0; k < NCL; k += 4) {
            float4 sb[4];
            #pragma unroll
            for (int r = 0; r < 4; ++r)
                sb[r] = *(const float4*)&h_lds[(nd0 + r) * NCL + k];
            #pragma unroll
            for (int kk = 0; kk < 4; ++kk) {
                const float wv = wbuf[(k + kk) * NCL + lane];
                #pragma unroll
                for (int r = 0; r < 4; ++r)
                    acc[r] = fmaf(f4c(sb[r], kk), wv, acc[r]);
            }
        }
        #pragma unroll
        for (int r = 0; r < 4; ++r) ssum += acc[r] + hreg[r];
    }
    __syncthreads();

    // ---------------- A_rel = s@Wa + b_rel0 ; B_rel = s@Wb ----------------
    for (int idx = tid; idx < 129 * 128; idx += NT) wbuf[idx] = W_rel0[idx];
    __syncthreads();
    {
        const float ba = b_rel0[lane], bb = b_rel0[64 + lane];
        float aA0[4] = {ba, ba, ba, ba}, aA1[4] = {bb, bb, bb, bb};
        float aB0[4] = {0, 0, 0, 0},     aB1[4] = {0, 0, 0, 0};
        for (int k = 0; k < NCL; k += 4) {
            float4 sb[4];
            #pragma unroll
            for (int r = 0; r < 4; ++r)
                sb[r] = *(const float4*)&encl[nd0 + r][k];
            #pragma unroll
            for (int kk = 0; kk < 4; ++kk) {
                const float wa0 = wbuf[(k + kk) * 128 + lane];
                const float wa1 = wbuf[(k + kk) * 128 + 64 + lane];
                const float wb0 = wbuf[(64 + k + kk) * 128 + lane];
                const float wb1 = wbuf[(64 + k + kk) * 128 + 64 + lane];
                #pragma unroll
                for (int r = 0; r < 4; ++r) {
                    const float v = f4c(sb[r], kk);
                    aA0[r] = fmaf(v, wa0, aA0[r]);
                    aA1[r] = fmaf(v, wa1, aA1[r]);
                    aB0[r] = fmaf(v, wb0, aB0[r]);
                    aB1[r] = fmaf(v, wb1, aB1[r]);
                }
            }
        }
        #pragma unroll
        for (int r = 0; r < 4; ++r) {
            AB[0][nd0 + r][lane] = aA0[r];  AB[0][nd0 + r][64 + lane] = aA1[r];
            AB[1][nd0 + r][lane] = aB0[r];  AB[1][nd0 + r][64 + lane] = aB1[r];
        }
    }
    const float wdr0 = W_rel0[128 * 128 + lane];
    const float wdr1 = W_rel0[128 * 128 + 64 + lane];
    __syncthreads();

    // ---------------- A_att / B_att ----------------
    for (int idx = tid; idx < 129 * 128; idx += NT) wbuf[idx] = W_att0[idx];
    __syncthreads();
    {
        const float ba = b_att0[lane], bb = b_att0[64 + lane];
        float aA0[4] = {ba, ba, ba, ba}, aA1[4] = {bb, bb, bb, bb};
        float aB0[4] = {0, 0, 0, 0},     aB1[4] = {0, 0, 0, 0};
        for (int k = 0; k < NCL; k += 4) {
            float4 sb[4];
            #pragma unroll
            for (int r = 0; r < 4; ++r)
                sb[r] = *(const float4*)&encl[nd0 + r][k];
            #pragma unroll
            for (int kk = 0; kk < 4; ++kk) {
                const float wa0 = wbuf[(k + kk) * 128 + lane];
                const float wa1 = wbuf[(k + kk) * 128 + 64 + lane];
                const float wb0 = wbuf[(64 + k + kk) * 128 + lane];
                const float wb1 = wbuf[(64 + k + kk) * 128 + 64 + lane];
                #pragma unroll
                for (int r = 0; r < 4; ++r) {
                    const float v = f4c(sb[r], kk);
                    aA0[r] = fmaf(v, wa0, aA0[r]);
                    aA1[r] = fmaf(v, wa1, aA1[r]);
                    aB0[r] = fmaf(v, wb0, aB0[r]);
                    aB1[r] = fmaf(v, wb1, aB1[r]);
                }
            }
        }
        #pragma unroll
        for (int r = 0; r < 4; ++r) {
            AB[2][nd0 + r][lane] = aA0[r];  AB[2][nd0 + r][64 + lane] = aA1[r];
            AB[3][nd0 + r][lane] = aB0[r];  AB[3][nd0 + r][64 + lane] = aB1[r];
        }
    }
    const float wda0 = W_att0[128 * 128 + lane];
    const float wda1 = W_att0[128 * 128 + 64 + lane];
    __syncthreads();

    // ---------------- pass A: attention scalars ----------------
    for (int idx = tid; idx < 128 * 64; idx += NT) wbuf[idx] = W_att1[idx];
    __syncthreads();
    {
        const float wa2  = W_att2[lane];
        const float ba1v = b_att1[lane];
        const float ba2v = b_att2[0];
        const int   bl   = w >> 1;
        float aA0[4], aA1[4], pix[4], piy[4];
        #pragma unroll
        for (int r = 0; r < 4; ++r) {
            aA0[r] = AB[2][nd0 + r][lane];
            aA1[r] = AB[2][nd0 + r][64 + lane];
            pix[r] = posl[nd0 + r][0];
            piy[r] = posl[nd0 + r][1];
        }
        for (int j = 0; j < NN; ++j) {
            const int nj = bl * NN + j;
            const float pjx = posl[nj][0], pjy = posl[nj][1];
            const float bB0 = AB[3][nj][lane], bB1 = AB[3][nj][64 + lane];
            #pragma unroll
            for (int r = 0; r < 4; ++r) {
                const float dx = pix[r] - pjx, dy = piy[r] - pjy;
                const float d  = dx * dx + dy * dy;
                sc[w][r][lane]      = elu_f(aA0[r] + bB0 + d * wda0);
                sc[w][r][64 + lane] = elu_f(aA1[r] + bB1 + d * wda1);
            }
            float acc[4] = {ba1v, ba1v, ba1v, ba1v};
            for (int k = 0; k < 128; k += 4) {
                float wv[4];
                #pragma unroll
                for (int kk = 0; kk < 4; ++kk) wv[kk] = wbuf[(k + kk) * 64 + lane];
                #pragma unroll
                for (int r = 0; r < 4; ++r) {
                    const float4 sb = *(const float4*)&sc[w][r][k];
                    acc[r] = fmaf(sb.x, wv[0], acc[r]);
                    acc[r] = fmaf(sb.y, wv[1], acc[r]);
                    acc[r] = fmaf(sb.z, wv[2], acc[r]);
                    acc[r] = fmaf(sb.w, wv[3], acc[r]);
                }
            }
            #pragma unroll
            for (int r = 0; r < 4; ++r) {
                float t = elu_f(acc[r]) * wa2;
                #pragma unroll
                for (int off = 32; off > 0; off >>= 1) t += __shfl_xor(t, off, 64);
                if (lane == 0) attl[w][r][j] = 1.0f / (1.0f + __expf(-(t + ba2v)));
            }
        }
    }
    __syncthreads();

    // ---------------- pass B: rel path + masked accumulate ----------------
    for (int idx = tid; idx < 128 * 64; idx += NT) wbuf[idx] = W_rel1[idx];
    for (int idx = tid; idx < 64 * 64;  idx += NT) wbuf[128 * 64 + idx] = W_rel2[idx];
    __syncthreads();
    float relsum = 0.0f;
    {
        const float br1 = b_rel1[lane], br2 = b_rel2[lane];
        const int   bl  = w >> 1;
        const int   i0  = (w & 1) * 4;
        float aA0[4], aA1[4], pix[4], piy[4], racc[4] = {0, 0, 0, 0};
        #pragma unroll
        for (int r = 0; r < 4; ++r) {
            aA0[r] = AB[0][nd0 + r][lane];
            aA1[r] = AB[0][nd0 + r][64 + lane];
            pix[r] = posl[nd0 + r][0];
            piy[r] = posl[nd0 + r][1];
        }
        for (int j = 0; j < NN; ++j) {
            const int nj = bl * NN + j;
            const float pjx = posl[nj][0], pjy = posl[nj][1];
            const float bB0 = AB[1][nj][lane], bB1 = AB[1][nj][64 + lane];
            #pragma unroll
            for (int r = 0; r < 4; ++r) {
                const float dx = pix[r] - pjx, dy = piy[r] - pjy;
                const float d  = dx * dx + dy * dy;
                sc[w][r][lane]      = elu_f(aA0[r] + bB0 + d * wdr0);
                sc[w][r][64 + lane] = elu_f(aA1[r] + bB1 + d * wdr1);
            }
            float acc[4] = {br1, br1, br1, br1};
            for (int k = 0; k < 128; k += 4) {
                float wv[4];
                #pragma unroll
                for (int kk = 0; kk < 4; ++kk) wv[kk] = wbuf[(k + kk) * 64 + lane];
                #pragma unroll
                for (int r = 0; r < 4; ++r) {
                    const float4 sb = *(const float4*)&sc[w][r][k];
                    acc[r] = fmaf(sb.x, wv[0], acc[r]);
                    acc[r] = fmaf(sb.y, wv[1], acc[r]);
                    acc[r] = fmaf(sb.z, wv[2], acc[r]);
                    acc[r] = fmaf(sb.w, wv[3], acc[r]);
                }
            }
            float r2[4];
            #pragma unroll
            for (int r = 0; r < 4; ++r) r2[r] = elu_f(acc[r]);
            #pragma unroll
            for (int r = 0; r < 4; ++r) sc[w][r][lane] = r2[r];   // overwrite low half
            float acc3[4] = {br2, br2, br2, br2};
            for (int k = 0; k < 64; k += 4) {
                float wv[4];
                #pragma unroll
                for (int kk = 0; kk < 4; ++kk) wv[kk] = wbuf[128 * 64 + (k + kk) * 64 + lane];
                #pragma unroll
                for (int r = 0; r < 4; ++r) {
                    const float4 sb = *(const float4*)&sc[w][r][k];
                    acc3[r] = fmaf(sb.x, wv[0], acc3[r]);
                    acc3[r] = fmaf(sb.y, wv[1], acc3[r]);
                    acc3[r] = fmaf(sb.z, wv[2], acc3[r]);
                    acc3[r] = fmaf(sb.w, wv[3], acc3[r]);
                }
            }
            #pragma unroll
            for (int r = 0; r < 4; ++r) {
                const float relf = acc3[r] + r2[r];
                const float am   = (j == i0 + r) ? 0.0f : attl[w][r][j];
                racc[r] = fmaf(relf, am, racc[r]);
            }
        }
        relsum = racc[0] + racc[1] + racc[2] + racc[3];
    }
    fin[w][lane] = ssum + relsum;
    __syncthreads();

    // ---------------- output: sum over i (two waves per batch element) ----------------
    if (tid < NG * 64) {
        const int bl = tid >> 6, c = tid & 63;
        Out[(size_t)(b0 + bl) * 64 + c] = fin[2 * bl][c] + fin[2 * bl + 1][c];
    }
}

extern "C" void kernel_launch(void* const* d_in, const int* in_sizes, int n_in,
                              void* d_out, int out_size, void* d_ws, size_t ws_size,
                              hipStream_t stream) {
    const float* S       = (const float*)d_in[0];
    const float* W_enc   = (const float*)d_in[1];
    const float* b_enc   = (const float*)d_in[2];
    const float* W_self0 = (const float*)d_in[3];
    const float* b_self0 = (const float*)d_in[4];
    const float* W_self1 = (const float*)d_in[5];
    const float* b_self1 = (const float*)d_in[6];
    const float* W_rel0  = (const float*)d_in[7];
    const float* b_rel0  = (const float*)d_in[8];
    const float* W_rel1  = (const float*)d_in[9];
    const float* b_rel1  = (const float*)d_in[10];
    const float* W_rel2  = (const float*)d_in[11];
    const float* b_rel2  = (const float*)d_in[12];
    const float* W_att0  = (const float*)d_in[13];
    const float* b_att0  = (const float*)d_in[14];
    const float* W_att1  = (const float*)d_in[15];
    const float* b_att1  = (const float*)d_in[16];
    const float* W_att2  = (const float*)d_in[17];
    const float* b_att2  = (const float*)d_in[18];

    const int nB   = in_sizes[0] / (NN * NCL);   // 8192
    const int grid = nB / NG;                    // 2048

    gh_kernel<<<dim3(grid), dim3(NT), 0, stream>>>(
        S, W_enc, b_enc, W_self0, b_self0, W_self1, b_self1,
        W_rel0, b_rel0, W_rel1, b_rel1, W_rel2, b_rel2,
        W_att0, b_att0, W_att1, b_att1, W_att2, b_att2,
        (float*)d_out);
}

// Round 2
// 386.147 us; speedup vs baseline: 14.0321x; 14.0321x over previous
//
#include <hip/hip_runtime.h>
#include <math.h>

constexpr int NCL = 64;
constexpr int NN  = 8;
constexpr int NG  = 4;     // batch elems per block
constexpr int NT  = 512;   // 8 waves

typedef __attribute__((ext_vector_type(4))) float f32x4;
typedef __attribute__((ext_vector_type(8))) short s16x8;
#define MFMA __builtin_amdgcn_mfma_f32_16x16x32_bf16

__device__ __forceinline__ float elu_f(float x) { return x > 0.f ? x : __expf(x) - 1.f; }

__device__ __forceinline__ unsigned short bfh(float x) {
    union { float f; unsigned u; } c; c.f = x;
    return (unsigned short)((c.u + 0x7fffu + ((c.u >> 16) & 1u)) >> 16);
}
__device__ __forceinline__ float bff(unsigned short h) {
    union { unsigned u; float f; } c; c.u = ((unsigned)h) << 16; return c.f;
}
__device__ __forceinline__ void split2(float x, short& hi, short& lo) {
    unsigned short h = bfh(x);
    hi = (short)h;
    lo = (short)bfh(x - bff(h));
}

// A-fragment (split hi/lo) from an activation LDS buffer with row stride 68.
__device__ __forceinline__ void afrag_split(const float* act, int row, int kbase,
                                            s16x8& hi, s16x8& lo) {
    const float4 v0 = *(const float4*)(act + row * 68 + kbase);
    const float4 v1 = *(const float4*)(act + row * 68 + kbase + 4);
    float v[8] = {v0.x, v0.y, v0.z, v0.w, v1.x, v1.y, v1.z, v1.w};
    #pragma unroll
    for (int e = 0; e < 8; ++e) { short a, b; split2(v[e], a, b); hi[e] = a; lo[e] = b; }
}

// B-fragment (split) straight from a global row-major [K][N] weight matrix.
__device__ __forceinline__ void bfrag_g(const float* __restrict__ W, int N, int kbase, int col,
                                        s16x8& hi, s16x8& lo) {
    #pragma unroll
    for (int e = 0; e < 8; ++e) {
        short a, b; split2(W[(kbase + e) * N + col], a, b); hi[e] = a; lo[e] = b;
    }
}

// B-fragment (split) from LDS-staged weights, row stride 69.
__device__ __forceinline__ void wfrag_l(const float* wl, int kg, int nt, int lane,
                                        s16x8& hi, s16x8& lo) {
    const int kbase = kg * 32 + (lane >> 4) * 8;
    const int col   = nt * 16 + (lane & 15);
    #pragma unroll
    for (int e = 0; e < 8; ++e) {
        short a, b; split2(wl[(kbase + e) * 69 + col], a, b); hi[e] = a; lo[e] = b;
    }
}

// One 16x16 output tile of act[32x64] @ W[64xN], split-bf16 (3 MFMAs / k-group).
__device__ __forceinline__ f32x4 node_tile(const float* act, const float* __restrict__ W, int N,
                                           int mt, int nt, int lane) {
    const int row = mt * 16 + (lane & 15);
    const int g   = lane >> 4;
    const int col = nt * 16 + (lane & 15);
    f32x4 acc = {0.f, 0.f, 0.f, 0.f};
    #pragma unroll
    for (int kg = 0; kg < 2; ++kg) {
        s16x8 ah, al, bh, bl;
        afrag_split(act, row, kg * 32 + g * 8, ah, al);
        bfrag_g(W, N, kg * 32 + g * 8, col, bh, bl);
        acc = MFMA(ah, bh, acc, 0, 0, 0);
        acc = MFMA(ah, bl, acc, 0, 0, 0);
        acc = MFMA(al, bh, acc, 0, 0, 0);
    }
    return acc;
}

// X1 pair-feature fragment (split): elu(A[i][f] + B[j][f] + d*wd[f]), f = kg*32+g*8..+7
__device__ __forceinline__ void x1frag(const float* Ab, const float* Bb,
                                       const float* __restrict__ wdg, const float* d2p,
                                       int baseA, int baseB, int ihalf, int mt, int kg, int lane,
                                       s16x8& hi, s16x8& lo) {
    const int p  = (lane & 15) + 16 * mt;
    const int il = p >> 3, j = p & 7, g = lane >> 4;
    const int f  = kg * 32 + g * 8;
    const float4 a0 = *(const float4*)(Ab + (baseA + il) * 132 + f);
    const float4 a1 = *(const float4*)(Ab + (baseA + il) * 132 + f + 4);
    const float4 c0 = *(const float4*)(Bb + (baseB + j) * 132 + f);
    const float4 c1 = *(const float4*)(Bb + (baseB + j) * 132 + f + 4);
    const float  d  = d2p[(ihalf * 4 + il) * 8 + j];
    const float4 w0 = *(const float4*)(wdg + f);
    const float4 w1 = *(const float4*)(wdg + f + 4);
    float v[8];
    v[0] = elu_f(a0.x + c0.x + d * w0.x);
    v[1] = elu_f(a0.y + c0.y + d * w0.y);
    v[2] = elu_f(a0.z + c0.z + d * w0.z);
    v[3] = elu_f(a0.w + c0.w + d * w0.w);
    v[4] = elu_f(a1.x + c1.x + d * w1.x);
    v[5] = elu_f(a1.y + c1.y + d * w1.y);
    v[6] = elu_f(a1.z + c1.z + d * w1.z);
    v[7] = elu_f(a1.w + c1.w + d * w1.w);
    #pragma unroll
    for (int e = 0; e < 8; ++e) { short a, b; split2(v[e], a, b); hi[e] = a; lo[e] = b; }
}

__global__ __launch_bounds__(NT)
void gh_kernel(const float* __restrict__ S,
               const float* __restrict__ W_enc,  const float* __restrict__ b_enc,
               const float* __restrict__ W_self0,const float* __restrict__ b_self0,
               const float* __restrict__ W_self1,const float* __restrict__ b_self1,
               const float* __restrict__ W_rel0, const float* __restrict__ b_rel0,
               const float* __restrict__ W_rel1, const float* __restrict__ b_rel1,
               const float* __restrict__ W_rel2, const float* __restrict__ b_rel2,
               const float* __restrict__ W_att0, const float* __restrict__ b_att0,
               const float* __restrict__ W_att1, const float* __restrict__ b_att1,
               const float* __restrict__ W_att2, const float* __restrict__ b_att2,
               float* __restrict__ Out)
{
    // LDS: 4*8704 + 4*16896 + 35328 + 1024 + 128 + 1088 = 139,968 B (< 160 KiB)
    __shared__ __align__(16) float sbuf[32 * 68];   // s; later aliased as self_dyn rows
    __shared__ __align__(16) float encb[32 * 68];
    __shared__ __align__(16) float hbuf[32 * 68];
    __shared__ __align__(16) float Tbuf[32 * 68];
    __shared__ __align__(16) float ABm[4][32 * 132]; // 0:Ar 1:Br 2:Aa 3:Ba
    __shared__ __align__(16) float wst[128 * 69];
    __shared__ float d2l[4 * 64];
    __shared__ float cntl[32];
    __shared__ float Ubuf[4 * 68];

    const int tid  = threadIdx.x;
    const int w    = tid >> 6;
    const int lane = tid & 63;
    const int g    = lane >> 4;
    const int b0   = blockIdx.x * NG;
    float* sd = sbuf;   // alias: self_dyn rows overwrite s after enc phase

    // ---- P0: load s ----
    {
        const float* src = S + (size_t)b0 * NN * NCL;
        for (int idx = tid; idx < 32 * 64; idx += NT) {
            sbuf[(idx >> 6) * 68 + (idx & 63)] = src[idx];
        }
    }
    __syncthreads();

    // d2 (consumed in pair passes; covered by later syncs)
    if (tid < 256) {
        const int bi = tid >> 6, i = (tid >> 3) & 7, j = tid & 7;
        const float dx = sbuf[(bi * 8 + i) * 68 + 0] - sbuf[(bi * 8 + j) * 68 + 0];
        const float dy = sbuf[(bi * 8 + i) * 68 + 1] - sbuf[(bi * 8 + j) * 68 + 1];
        d2l[bi * 64 + i * 8 + j] = dx * dx + dy * dy;
    }

    // ---- P1: enc = concat(s[:2], (s@W_enc+b)[2:]) ----
    {
        const int mt = w & 1, nt = w >> 1;
        f32x4 acc = node_tile(sbuf, W_enc, 64, mt, nt, lane);
        const int   col = nt * 16 + (lane & 15);
        const float be  = b_enc[col];
        #pragma unroll
        for (int reg = 0; reg < 4; ++reg) {
            const int row = mt * 16 + g * 4 + reg;
            float v = acc[reg] + be;
            if (col < 2) v = sbuf[row * 68 + col];
            encb[row * 68 + col] = v;
        }
    }
    __syncthreads();

    // ---- P2: h = elu(enc @ W_self0 + b) ----
    {
        const int mt = w & 1, nt = w >> 1;
        f32x4 acc = node_tile(encb, W_self0, 64, mt, nt, lane);
        const int   col = nt * 16 + (lane & 15);
        const float bs  = b_self0[col];
        #pragma unroll
        for (int reg = 0; reg < 4; ++reg) {
            const int row = mt * 16 + g * 4 + reg;
            hbuf[row * 68 + col] = elu_f(acc[reg] + bs);
        }
    }
    __syncthreads();

    // ---- P3: stage W_att1; self1; Ar/Br/Aa/Ba ----
    for (int idx = tid; idx < 128 * 64; idx += NT)
        wst[(idx >> 6) * 69 + (idx & 63)] = W_att1[idx];
    {   // self_dyn rows = h@W_self1 + b + h   (overwrites sbuf)
        const int mt = w & 1, nt = w >> 1;
        f32x4 acc = node_tile(hbuf, W_self1, 64, mt, nt, lane);
        const int   col = nt * 16 + (lane & 15);
        const float bs  = b_self1[col];
        #pragma unroll
        for (int reg = 0; reg < 4; ++reg) {
            const int row = mt * 16 + g * 4 + reg;
            sd[row * 68 + col] = acc[reg] + bs + hbuf[row * 68 + col];
        }
    }
    {   // pair-linear node projections (A-frags shared across all 4 matrices)
        const int mt  = w >> 2;
        const int row = mt * 16 + (lane & 15);
        s16x8 eh[2], el[2];
        afrag_split(encb, row, 0 * 32 + g * 8, eh[0], el[0]);
        afrag_split(encb, row, 1 * 32 + g * 8, eh[1], el[1]);
        const float* Wp[4] = {W_rel0, W_rel0 + 64 * 128, W_att0, W_att0 + 64 * 128};
        #pragma unroll
        for (int t = 0; t < 2; ++t) {
            const int nt  = 2 * (w & 3) + t;
            const int col = nt * 16 + (lane & 15);
            #pragma unroll
            for (int m = 0; m < 4; ++m) {
                f32x4 acc = {0.f, 0.f, 0.f, 0.f};
                #pragma unroll
                for (int kg = 0; kg < 2; ++kg) {
                    s16x8 bh, bl;
                    bfrag_g(Wp[m], 128, kg * 32 + g * 8, col, bh, bl);
                    acc = MFMA(eh[kg], bh, acc, 0, 0, 0);
                    acc = MFMA(eh[kg], bl, acc, 0, 0, 0);
                    acc = MFMA(el[kg], bh, acc, 0, 0, 0);
                }
                const float badd = (m == 0) ? b_rel0[col] : (m == 2) ? b_att0[col] : 0.f;
                #pragma unroll
                for (int reg = 0; reg < 4; ++reg) {
                    const int orow = mt * 16 + g * 4 + reg;
                    ABm[m][orow * 132 + col] = acc[reg] + badd;
                }
            }
        }
    }
    __syncthreads();

    // ---- P4: attention pass (att kept in registers) ----
    float attreg[2][4];
    {
        const int bi = w >> 1, ihalf = w & 1;
        const float* wdA = W_att0 + 128 * 128;
        const float* d2p = &d2l[bi * 64];
        const float  ba2 = b_att2[0];
        float wa2v[4], ba1v[4];
        #pragma unroll
        for (int nt = 0; nt < 4; ++nt) {
            wa2v[nt] = W_att2[nt * 16 + (lane & 15)];
            ba1v[nt] = b_att1[nt * 16 + (lane & 15)];
        }
        #pragma unroll
        for (int mt = 0; mt < 2; ++mt) {
            s16x8 ah[4], al[4];
            #pragma unroll
            for (int kg = 0; kg < 4; ++kg)
                x1frag(ABm[2], ABm[3], wdA, d2p, bi * 8 + ihalf * 4, bi * 8,
                       ihalf, mt, kg, lane, ah[kg], al[kg]);
            f32x4 acc[4];
            #pragma unroll
            for (int nt = 0; nt < 4; ++nt) {
                acc[nt] = {ba1v[nt], ba1v[nt], ba1v[nt], ba1v[nt]};
                #pragma unroll
                for (int kg = 0; kg < 4; ++kg) {
                    s16x8 bh, bl;
                    wfrag_l(wst, kg, nt, lane, bh, bl);
                    acc[nt] = MFMA(ah[kg], bh, acc[nt], 0, 0, 0);
                    acc[nt] = MFMA(ah[kg], bl, acc[nt], 0, 0, 0);
                    acc[nt] = MFMA(al[kg], bh, acc[nt], 0, 0, 0);
                }
            }
            #pragma unroll
            for (int reg = 0; reg < 4; ++reg) {
                float s = 0.f;
                #pragma unroll
                for (int nt = 0; nt < 4; ++nt) s += elu_f(acc[nt][reg]) * wa2v[nt];
                s += __shfl_xor(s, 1, 64);
                s += __shfl_xor(s, 2, 64);
                s += __shfl_xor(s, 4, 64);
                s += __shfl_xor(s, 8, 64);
                attreg[mt][reg] = 1.f / (1.f + __expf(-(s + ba2)));
            }
        }
    }
    __syncthreads();

    // ---- P5: stage W_rel1 ----
    for (int idx = tid; idx < 128 * 64; idx += NT)
        wst[(idx >> 6) * 69 + (idx & 63)] = W_rel1[idx];
    __syncthreads();

    // ---- P6: rel pass -> T, cnt ----
    {
        const int bi = w >> 1, ihalf = w & 1;
        const float* wdR = W_rel0 + 128 * 128;
        const float* d2p = &d2l[bi * 64];
        float br1v[4];
        #pragma unroll
        for (int nt = 0; nt < 4; ++nt) br1v[nt] = b_rel1[nt * 16 + (lane & 15)];
        #pragma unroll
        for (int mt = 0; mt < 2; ++mt) {
            s16x8 ah[4], al[4];
            #pragma unroll
            for (int kg = 0; kg < 4; ++kg)
                x1frag(ABm[0], ABm[1], wdR, d2p, bi * 8 + ihalf * 4, bi * 8,
                       ihalf, mt, kg, lane, ah[kg], al[kg]);
            f32x4 acc[4];
            #pragma unroll
            for (int nt = 0; nt < 4; ++nt) {
                acc[nt] = {br1v[nt], br1v[nt], br1v[nt], br1v[nt]};
                #pragma unroll
                for (int kg = 0; kg < 4; ++kg) {
                    s16x8 bh, bl;
                    wfrag_l(wst, kg, nt, lane, bh, bl);
                    acc[nt] = MFMA(ah[kg], bh, acc[nt], 0, 0, 0);
                    acc[nt] = MFMA(ah[kg], bl, acc[nt], 0, 0, 0);
                    acc[nt] = MFMA(al[kg], bh, acc[nt], 0, 0, 0);
                }
            }
            // coefficients: masked attention per pair-row owned by this lane's (g, reg)
            const int ifull = ihalf * 4 + 2 * mt + (g >> 1);
            float coef[4], cpart = 0.f;
            #pragma unroll
            for (int reg = 0; reg < 4; ++reg) {
                const int jj = 4 * (g & 1) + reg;
                coef[reg] = (jj == ifull) ? 0.f : attreg[mt][reg];
                cpart += coef[reg];
            }
            const float csum = cpart + __shfl_xor(cpart, 16, 64);
            if (((g & 1) == 0) && ((lane & 15) == 0))
                cntl[bi * 8 + ifull] = csum;
            #pragma unroll
            for (int nt = 0; nt < 4; ++nt) {
                float tpart = 0.f;
                #pragma unroll
                for (int reg = 0; reg < 4; ++reg)
                    tpart += coef[reg] * elu_f(acc[nt][reg]);
                const float tsum = tpart + __shfl_xor(tpart, 16, 64);
                if ((g & 1) == 0)
                    Tbuf[(bi * 8 + ifull) * 68 + nt * 16 + (lane & 15)] = tsum;
            }
        }
    }
    __syncthreads();

    // ---- P7a: U[b] = sum_i T[i] ----
    if (tid < 256) {
        const int b = tid >> 6, c = tid & 63;
        float u = 0.f;
        #pragma unroll
        for (int i = 0; i < 8; ++i) u += Tbuf[(b * 8 + i) * 68 + c];
        Ubuf[b * 68 + c] = u;
    }
    __syncthreads();

    // ---- P7b: Out = sum_i sd + U@W_rel2 + C*b_rel2 + U ----
    if (tid < 256) {
        const int b = tid >> 6, c = tid & 63;
        float sds = 0.f, C = 0.f;
        #pragma unroll
        for (int i = 0; i < 8; ++i) {
            sds += sd[(b * 8 + i) * 68 + c];
            C   += cntl[b * 8 + i];
        }
        float r = 0.f;
        for (int k = 0; k < 64; ++k)
            r += Ubuf[b * 68 + k] * W_rel2[k * 64 + c];
        Out[(size_t)(b0 + b) * 64 + c] = sds + r + C * b_rel2[c] + Ubuf[b * 68 + c];
    }
}

extern "C" void kernel_launch(void* const* d_in, const int* in_sizes, int n_in,
                              void* d_out, int out_size, void* d_ws, size_t ws_size,
                              hipStream_t stream) {
    const float* S       = (const float*)d_in[0];
    const float* W_enc   = (const float*)d_in[1];
    const float* b_enc   = (const float*)d_in[2];
    const float* W_self0 = (const float*)d_in[3];
    const float* b_self0 = (const float*)d_in[4];
    const float* W_self1 = (const float*)d_in[5];
    const float* b_self1 = (const float*)d_in[6];
    const float* W_rel0  = (const float*)d_in[7];
    const float* b_rel0  = (const float*)d_in[8];
    const float* W_rel1  = (const float*)d_in[9];
    const float* b_rel1  = (const float*)d_in[10];
    const float* W_rel2  = (const float*)d_in[11];
    const float* b_rel2  = (const float*)d_in[12];
    const float* W_att0  = (const float*)d_in[13];
    const float* b_att0  = (const float*)d_in[14];
    const float* W_att1  = (const float*)d_in[15];
    const float* b_att1  = (const float*)d_in[16];
    const float* W_att2  = (const float*)d_in[17];
    const float* b_att2  = (const float*)d_in[18];

    const int nB   = in_sizes[0] / (NN * NCL);   // 8192
    const int grid = nB / NG;                    // 2048

    gh_kernel<<<dim3(grid), dim3(NT), 0, stream>>>(
        S, W_enc, b_enc, W_self0, b_self0, W_self1, b_self1,
        W_rel0, b_rel0, W_rel1, b_rel1, W_rel2, b_rel2,
        W_att0, b_att0, W_att1, b_att1, W_att2, b_att2,
        (float*)d_out);
}

// Round 4
// 244.993 us; speedup vs baseline: 22.1166x; 1.5762x over previous
//
#include <hip/hip_runtime.h>
#include <math.h>

constexpr int NCL = 64;
constexpr int NN  = 8;
constexpr int NG  = 4;      // batch elems per block
constexpr int NT  = 1024;   // 16 waves

typedef __attribute__((ext_vector_type(4))) float f32x4;
typedef __attribute__((ext_vector_type(8))) short s16x8;
#define MFMA __builtin_amdgcn_mfma_f32_16x16x32_bf16

// workspace layout offsets (units of s16x8 = 16 B)
constexpr int OFF_ENC = 0;      // 8 frags  (hi 512 | lo 512)
constexpr int OFF_S0  = 1024;
constexpr int OFF_S1  = 2048;
constexpr int OFF_R0  = 3072;   // 32 frags (hi 2048 | lo 2048)
constexpr int OFF_A0  = 7168;
constexpr int OFF_A1  = 11264;  // 16 frags (hi 1024 | lo 1024)
constexpr int OFF_R1  = 13312;

__device__ __forceinline__ float elu_f(float x) { return x > 0.f ? x : __expf(x) - 1.f; }

__device__ __forceinline__ short bfh_rn(float x) {
    union { float f; unsigned u; } c; c.f = x;
    return (short)((c.u + 0x7fffu + ((c.u >> 16) & 1u)) >> 16);
}
// hi = truncated bf16, lo = rounded residual (exact compensation, err ~2^-17)
__device__ __forceinline__ void split_tr(float x, short& hi, short& lo) {
    union { float f; unsigned u; } c; c.f = x;
    hi = (short)(c.u >> 16);
    union { unsigned u; float f; } t; t.u = c.u & 0xffff0000u;
    lo = bfh_rn(x - t.f);
}

// A-fragment (split hi/lo) from fp32 LDS activations, row stride 68.
__device__ __forceinline__ void afrag_split(const float* act, int row, int kbase,
                                            s16x8& hi, s16x8& lo) {
    const float4 v0 = *(const float4*)(act + row * 68 + kbase);
    const float4 v1 = *(const float4*)(act + row * 68 + kbase + 4);
    float v[8] = {v0.x, v0.y, v0.z, v0.w, v1.x, v1.y, v1.z, v1.w};
    #pragma unroll
    for (int e = 0; e < 8; ++e) { short a, b; split_tr(v[e], a, b); hi[e] = a; lo[e] = b; }
}

// 16x16 tile of act[32x64] @ W[64x64] from packed fragments (8-frag matrix).
__device__ __forceinline__ f32x4 node_tile_pk(const float* act, const s16x8* __restrict__ wb,
                                              int mt, int nt, int lane) {
    const int row = mt * 16 + (lane & 15);
    const int g   = lane >> 4;
    f32x4 acc = {0.f, 0.f, 0.f, 0.f};
    #pragma unroll
    for (int kg = 0; kg < 2; ++kg) {
        s16x8 ah, al;
        afrag_split(act, row, kg * 32 + g * 8, ah, al);
        const s16x8 bh = wb[(kg * 4 + nt) * 64 + lane];
        const s16x8 bl = wb[512 + (kg * 4 + nt) * 64 + lane];
        acc = MFMA(ah, bh, acc, 0, 0, 0);
        acc = MFMA(ah, bl, acc, 0, 0, 0);
        acc = MFMA(al, bh, acc, 0, 0, 0);
    }
    return acc;
}

// X1 pair-feature fragment: elu(A[f] + B[f] + d*wd[f]) for f = fbase..fbase+7
__device__ __forceinline__ void x1frag(const float* Arow, const float* Brow,
                                       const float* wdg, float d, int fbase,
                                       s16x8& hi, s16x8& lo) {
    const float4 a0 = *(const float4*)(Arow + fbase);
    const float4 a1 = *(const float4*)(Arow + fbase + 4);
    const float4 c0 = *(const float4*)(Brow + fbase);
    const float4 c1 = *(const float4*)(Brow + fbase + 4);
    const float4 w0 = *(const float4*)(wdg + fbase);
    const float4 w1 = *(const float4*)(wdg + fbase + 4);
    float v[8];
    v[0] = elu_f(a0.x + c0.x + d * w0.x);
    v[1] = elu_f(a0.y + c0.y + d * w0.y);
    v[2] = elu_f(a0.z + c0.z + d * w0.z);
    v[3] = elu_f(a0.w + c0.w + d * w0.w);
    v[4] = elu_f(a1.x + c1.x + d * w1.x);
    v[5] = elu_f(a1.y + c1.y + d * w1.y);
    v[6] = elu_f(a1.z + c1.z + d * w1.z);
    v[7] = elu_f(a1.w + c1.w + d * w1.w);
    #pragma unroll
    for (int e = 0; e < 8; ++e) { short a, b; split_tr(v[e], a, b); hi[e] = a; lo[e] = b; }
}

// ---------------- prep: pack weights into split-bf16 fragment planes ----------------
__global__ __launch_bounds__(64)
void prep_kernel(const float* __restrict__ We,  const float* __restrict__ Ws0,
                 const float* __restrict__ Ws1, const float* __restrict__ Wr0,
                 const float* __restrict__ Wa0, const float* __restrict__ Wa1,
                 const float* __restrict__ Wr1, s16x8* __restrict__ ws)
{
    const int b = blockIdx.x, lane = threadIdx.x;
    const float* W; int nnt, nfrag, base, frag;
    if      (b < 8)   { W = We;  nnt = 4; nfrag = 8;  base = OFF_ENC; frag = b; }
    else if (b < 16)  { W = Ws0; nnt = 4; nfrag = 8;  base = OFF_S0;  frag = b - 8; }
    else if (b < 24)  { W = Ws1; nnt = 4; nfrag = 8;  base = OFF_S1;  frag = b - 16; }
    else if (b < 56)  { W = Wr0; nnt = 8; nfrag = 32; base = OFF_R0;  frag = b - 24; }
    else if (b < 88)  { W = Wa0; nnt = 8; nfrag = 32; base = OFF_A0;  frag = b - 56; }
    else if (b < 104) { W = Wa1; nnt = 4; nfrag = 16; base = OFF_A1;  frag = b - 88; }
    else              { W = Wr1; nnt = 4; nfrag = 16; base = OFF_R1;  frag = b - 104; }
    const int kg = frag / nnt, nt = frag % nnt;
    const int N  = nnt * 16;
    const int g  = lane >> 4, col = nt * 16 + (lane & 15);
    s16x8 hi, lo;
    #pragma unroll
    for (int e = 0; e < 8; ++e) {
        short a, c; split_tr(W[(kg * 32 + g * 8 + e) * N + col], a, c);
        hi[e] = a; lo[e] = c;
    }
    ws[base + frag * 64 + lane]              = hi;
    ws[base + nfrag * 64 + frag * 64 + lane] = lo;
}

// ---------------- main ----------------
__global__ __launch_bounds__(NT, 1)
void gh_kernel(const float* __restrict__ S,
               const float* __restrict__ b_enc,
               const float* __restrict__ b_self0, const float* __restrict__ b_self1,
               const float* __restrict__ W_rel0,  const float* __restrict__ b_rel0,
               const float* __restrict__ b_rel1,
               const float* __restrict__ W_rel2,  const float* __restrict__ b_rel2,
               const float* __restrict__ W_att0,  const float* __restrict__ b_att0,
               const float* __restrict__ b_att1,
               const float* __restrict__ W_att2,  const float* __restrict__ b_att2,
               const s16x8* __restrict__ wp,
               float* __restrict__ Out)
{
    // LDS: 3*8704 + 67584 + 32768 + 1024 + 128 + 1088 + 1024 = 129,728 B
    __shared__ __align__(16) float sbuf[32 * 68];    // s; later self_dyn
    __shared__ __align__(16) float encb[32 * 68];
    __shared__ __align__(16) float hbuf[32 * 68];    // h; later Tbuf
    __shared__ __align__(16) float ABm[4][32 * 132]; // 0:Ar 1:Br 2:Aa 3:Ba
    __shared__ __align__(16) s16x8 wstp[2048];       // staged packed W_att1 / W_rel1
    __shared__ float d2l[4 * 64];
    __shared__ float cntl[32];
    __shared__ float Ubuf[4 * 68];
    __shared__ float wdl[2][128];                    // dist rows: 0 rel, 1 att

    const int tid  = threadIdx.x;
    const int w    = tid >> 6;
    const int lane = tid & 63;
    const int g    = lane >> 4;
    const int b0   = blockIdx.x * NG;
    float* sd = sbuf;
    float* Tb = hbuf;

    // ---- P0: load s, stage packed W_att1, load dist rows ----
    {
        const float* src = S + (size_t)b0 * NN * NCL;
        for (int idx = tid; idx < 32 * 64; idx += NT)
            sbuf[(idx >> 6) * 68 + (idx & 63)] = src[idx];
        for (int idx = tid; idx < 2048; idx += NT)
            wstp[idx] = wp[OFF_A1 + idx];
        if (tid < 128) {
            wdl[0][tid] = W_rel0[128 * 128 + tid];
            wdl[1][tid] = W_att0[128 * 128 + tid];
        }
    }
    __syncthreads();

    if (tid < 256) {
        const int bi = tid >> 6, i = (tid >> 3) & 7, j = tid & 7;
        const float dx = sbuf[(bi * 8 + i) * 68 + 0] - sbuf[(bi * 8 + j) * 68 + 0];
        const float dy = sbuf[(bi * 8 + i) * 68 + 1] - sbuf[(bi * 8 + j) * 68 + 1];
        d2l[bi * 64 + i * 8 + j] = dx * dx + dy * dy;
    }

    // ---- P1: enc (waves 0-7) ----
    if (w < 8) {
        const int mt = w & 1, nt = w >> 1;
        f32x4 acc = node_tile_pk(sbuf, wp + OFF_ENC, mt, nt, lane);
        const int   col = nt * 16 + (lane & 15);
        const float be  = b_enc[col];
        #pragma unroll
        for (int reg = 0; reg < 4; ++reg) {
            const int row = mt * 16 + g * 4 + reg;
            float v = acc[reg] + be;
            if (col < 2) v = sbuf[row * 68 + col];
            encb[row * 68 + col] = v;
        }
    }
    __syncthreads();

    // ---- P2: h = elu(enc @ W_self0 + b) (waves 0-7) ----
    if (w < 8) {
        const int mt = w & 1, nt = w >> 1;
        f32x4 acc = node_tile_pk(encb, wp + OFF_S0, mt, nt, lane);
        const int   col = nt * 16 + (lane & 15);
        const float bs  = b_self0[col];
        #pragma unroll
        for (int reg = 0; reg < 4; ++reg)
            hbuf[(mt * 16 + g * 4 + reg) * 68 + col] = elu_f(acc[reg] + bs);
    }
    __syncthreads();

    // ---- P3: self1 (waves 0-7) + pair projections (all 16 waves) ----
    if (w < 8) {
        const int mt = w & 1, nt = w >> 1;
        f32x4 acc = node_tile_pk(hbuf, wp + OFF_S1, mt, nt, lane);
        const int   col = nt * 16 + (lane & 15);
        const float bs  = b_self1[col];
        #pragma unroll
        for (int reg = 0; reg < 4; ++reg) {
            const int row = mt * 16 + g * 4 + reg;
            sd[row * 68 + col] = acc[reg] + bs + hbuf[row * 68 + col];
        }
    }
    {
        const int mtp = w >> 3, ntp = w & 7;
        const int row = mtp * 16 + (lane & 15);
        const int col = ntp * 16 + (lane & 15);
        s16x8 eh[2], el[2];
        afrag_split(encb, row, g * 8, eh[0], el[0]);
        afrag_split(encb, row, 32 + g * 8, eh[1], el[1]);
        #pragma unroll
        for (int m = 0; m < 4; ++m) {
            const s16x8* wb = wp + ((m < 2) ? OFF_R0 : OFF_A0);
            const int kgo = (m & 1) * 2;
            f32x4 acc = {0.f, 0.f, 0.f, 0.f};
            #pragma unroll
            for (int kg = 0; kg < 2; ++kg) {
                const s16x8 bh = wb[((kgo + kg) * 8 + ntp) * 64 + lane];
                const s16x8 bl = wb[2048 + ((kgo + kg) * 8 + ntp) * 64 + lane];
                acc = MFMA(eh[kg], bh, acc, 0, 0, 0);
                acc = MFMA(eh[kg], bl, acc, 0, 0, 0);
                acc = MFMA(el[kg], bh, acc, 0, 0, 0);
            }
            const float badd = (m == 0) ? b_rel0[col] : (m == 2) ? b_att0[col] : 0.f;
            #pragma unroll
            for (int reg = 0; reg < 4; ++reg)
                ABm[m][(mtp * 16 + g * 4 + reg) * 132 + col] = acc[reg] + badd;
        }
    }
    __syncthreads();

    // ---- P4: attention pass (att kept in registers) ----
    const int bi    = w >> 2;
    const int ihalf = (w >> 1) & 1;
    const int mt    = w & 1;
    const int pp    = (lane & 15) + 16 * mt;
    const int il    = pp >> 3, jj8 = pp & 7;
    const float* Arow_a = &ABm[2][(bi * 8 + ihalf * 4 + il) * 132];
    const float* Brow_a = &ABm[3][(bi * 8 + jj8) * 132];
    const float* Arow_r = &ABm[0][(bi * 8 + ihalf * 4 + il) * 132];
    const float* Brow_r = &ABm[1][(bi * 8 + jj8) * 132];
    const float dpair   = d2l[bi * 64 + (ihalf * 4 + il) * 8 + jj8];

    float attreg[4];
    {
        const float ba2 = b_att2[0];
        float wa2v[4], ba1v[4];
        #pragma unroll
        for (int nt = 0; nt < 4; ++nt) {
            wa2v[nt] = W_att2[nt * 16 + (lane & 15)];
            ba1v[nt] = b_att1[nt * 16 + (lane & 15)];
        }
        s16x8 ah[4], al[4];
        #pragma unroll
        for (int kg = 0; kg < 4; ++kg)
            x1frag(Arow_a, Brow_a, &wdl[1][0], dpair, kg * 32 + g * 8, ah[kg], al[kg]);
        f32x4 acc[4];
        #pragma unroll
        for (int nt = 0; nt < 4; ++nt) {
            acc[nt] = {ba1v[nt], ba1v[nt], ba1v[nt], ba1v[nt]};
            #pragma unroll
            for (int kg = 0; kg < 4; ++kg) {
                const s16x8 bh = wstp[(kg * 4 + nt) * 64 + lane];
                const s16x8 bl = wstp[1024 + (kg * 4 + nt) * 64 + lane];
                acc[nt] = MFMA(ah[kg], bh, acc[nt], 0, 0, 0);
                acc[nt] = MFMA(ah[kg], bl, acc[nt], 0, 0, 0);
                acc[nt] = MFMA(al[kg], bh, acc[nt], 0, 0, 0);
            }
        }
        #pragma unroll
        for (int reg = 0; reg < 4; ++reg) {
            float s = 0.f;
            #pragma unroll
            for (int nt = 0; nt < 4; ++nt) s += elu_f(acc[nt][reg]) * wa2v[nt];
            s += __shfl_xor(s, 1, 64);
            s += __shfl_xor(s, 2, 64);
            s += __shfl_xor(s, 4, 64);
            s += __shfl_xor(s, 8, 64);
            attreg[reg] = 1.f / (1.f + __expf(-(s + ba2)));
        }
    }
    __syncthreads();

    // ---- P5: stage packed W_rel1 ----
    for (int idx = tid; idx < 2048; idx += NT)
        wstp[idx] = wp[OFF_R1 + idx];
    __syncthreads();

    // ---- P6: rel pass -> T, cnt ----
    {
        float br1v[4];
        #pragma unroll
        for (int nt = 0; nt < 4; ++nt) br1v[nt] = b_rel1[nt * 16 + (lane & 15)];
        s16x8 ah[4], al[4];
        #pragma unroll
        for (int kg = 0; kg < 4; ++kg)
            x1frag(Arow_r, Brow_r, &wdl[0][0], dpair, kg * 32 + g * 8, ah[kg], al[kg]);
        f32x4 acc[4];
        #pragma unroll
        for (int nt = 0; nt < 4; ++nt) {
            acc[nt] = {br1v[nt], br1v[nt], br1v[nt], br1v[nt]};
            #pragma unroll
            for (int kg = 0; kg < 4; ++kg) {
                const s16x8 bh = wstp[(kg * 4 + nt) * 64 + lane];
                const s16x8 bl = wstp[1024 + (kg * 4 + nt) * 64 + lane];
                acc[nt] = MFMA(ah[kg], bh, acc[nt], 0, 0, 0);
                acc[nt] = MFMA(ah[kg], bl, acc[nt], 0, 0, 0);
                acc[nt] = MFMA(al[kg], bh, acc[nt], 0, 0, 0);
            }
        }
        // masked-attention coefficients; rows owned by (g, reg)
        const int ifull = ihalf * 4 + 2 * mt + (g >> 1);
        float coef[4], cpart = 0.f;
        #pragma unroll
        for (int reg = 0; reg < 4; ++reg) {
            const int jj = 4 * (g & 1) + reg;
            coef[reg] = (jj == ifull) ? 0.f : attreg[reg];
            cpart += coef[reg];
        }
        const float csum = cpart + __shfl_xor(cpart, 16, 64);
        if (((g & 1) == 0) && ((lane & 15) == 0))
            cntl[bi * 8 + ifull] = csum;
        #pragma unroll
        for (int nt = 0; nt < 4; ++nt) {
            float tpart = 0.f;
            #pragma unroll
            for (int reg = 0; reg < 4; ++reg)
                tpart += coef[reg] * elu_f(acc[nt][reg]);
            const float tsum = tpart + __shfl_xor(tpart, 16, 64);
            if ((g & 1) == 0)
                Tb[(bi * 8 + ifull) * 68 + nt * 16 + (lane & 15)] = tsum;
        }
    }
    __syncthreads();

    // ---- P7a: U[b] = sum_i T[i] ----
    if (tid < 256) {
        const int b = tid >> 6, c = tid & 63;
        float u = 0.f;
        #pragma unroll
        for (int i = 0; i < 8; ++i) u += Tb[(b * 8 + i) * 68 + c];
        Ubuf[b * 68 + c] = u;
    }
    __syncthreads();

    // ---- P7b: Out = sum_i sd + U@W_rel2 + C*b_rel2 + U ----
    if (tid < 256) {
        const int b = tid >> 6, c = tid & 63;
        float sds = 0.f, C = 0.f;
        #pragma unroll
        for (int i = 0; i < 8; ++i) {
            sds += sd[(b * 8 + i) * 68 + c];
            C   += cntl[b * 8 + i];
        }
        float r = 0.f;
        #pragma unroll 8
        for (int k = 0; k < 64; ++k)
            r += Ubuf[b * 68 + k] * W_rel2[k * 64 + c];
        Out[(size_t)(b0 + b) * 64 + c] = sds + r + C * b_rel2[c] + Ubuf[b * 68 + c];
    }
}

extern "C" void kernel_launch(void* const* d_in, const int* in_sizes, int n_in,
                              void* d_out, int out_size, void* d_ws, size_t ws_size,
                              hipStream_t stream) {
    const float* S       = (const float*)d_in[0];
    const float* W_enc   = (const float*)d_in[1];
    const float* b_enc   = (const float*)d_in[2];
    const float* W_self0 = (const float*)d_in[3];
    const float* b_self0 = (const float*)d_in[4];
    const float* W_self1 = (const float*)d_in[5];
    const float* b_self1 = (const float*)d_in[6];
    const float* W_rel0  = (const float*)d_in[7];
    const float* b_rel0  = (const float*)d_in[8];
    const float* W_rel1  = (const float*)d_in[9];
    const float* b_rel1  = (const float*)d_in[10];
    const float* W_rel2  = (const float*)d_in[11];
    const float* b_rel2  = (const float*)d_in[12];
    const float* W_att0  = (const float*)d_in[13];
    const float* b_att0  = (const float*)d_in[14];
    const float* W_att1  = (const float*)d_in[15];
    const float* b_att1  = (const float*)d_in[16];
    const float* W_att2  = (const float*)d_in[17];
    const float* b_att2  = (const float*)d_in[18];

    s16x8* wpk = (s16x8*)d_ws;

    prep_kernel<<<dim3(120), dim3(64), 0, stream>>>(
        W_enc, W_self0, W_self1, W_rel0, W_att0, W_att1, W_rel1, wpk);

    const int nB   = in_sizes[0] / (NN * NCL);   // 8192
    const int grid = nB / NG;                    // 2048

    gh_kernel<<<dim3(grid), dim3(NT), 0, stream>>>(
        S, b_enc, b_self0, b_self1,
        W_rel0, b_rel0, b_rel1, W_rel2, b_rel2,
        W_att0, b_att0, b_att1, W_att2, b_att2,
        wpk, (float*)d_out);
}

// Round 5
// 223.550 us; speedup vs baseline: 24.2381x; 1.0959x over previous
//
#include <hip/hip_runtime.h>
#include <math.h>

constexpr int NCL = 64;
constexpr int NN  = 8;
constexpr int NG  = 4;      // batch elems per block
constexpr int NT  = 1024;   // 16 waves

typedef __attribute__((ext_vector_type(4))) float f32x4;
typedef __attribute__((ext_vector_type(8))) short s16x8;
#define MFMA __builtin_amdgcn_mfma_f32_16x16x32_bf16

// workspace layout offsets (units of s16x8 = 16 B)
constexpr int OFF_ENC = 0;      // 8 frags  (hi 512 | lo 512)
constexpr int OFF_S0  = 1024;
constexpr int OFF_S1  = 2048;
constexpr int OFF_R0  = 3072;   // 32 frags (hi 2048 | lo 2048)
constexpr int OFF_A0  = 7168;
constexpr int OFF_A1  = 11264;  // 16 frags (hi 1024 | lo 1024)
constexpr int OFF_R1  = 13312;
constexpr int OFF_R2  = 15360;  // 8 frags  (hi 512 | lo 512)

__device__ __forceinline__ float elu_f(float x) { return x > 0.f ? x : __expf(x) - 1.f; }

__device__ __forceinline__ unsigned f2u(float x) { union { float f; unsigned u; } c; c.f = x; return c.u; }
__device__ __forceinline__ float u2f(unsigned u) { union { unsigned u; float f; } c; c.u = u; return c.f; }

// Pack 8 fp32 -> bf16 hi (truncated) + bf16 lo (truncated residual) fragments.
// err(hi+lo) <= 2^-16 |x| one-sided; 2 v_perm + 2 and + 2 sub per 2 elems.
__device__ __forceinline__ void splitpack8(const float v[8], s16x8& hi, s16x8& lo) {
    union { s16x8 s; unsigned u[4]; } H, L;
    #pragma unroll
    for (int e = 0; e < 8; e += 2) {
        H.u[e >> 1] = __builtin_amdgcn_perm(f2u(v[e + 1]), f2u(v[e]), 0x07060302u);
        const float t0 = u2f(f2u(v[e])     & 0xffff0000u);
        const float t1 = u2f(f2u(v[e + 1]) & 0xffff0000u);
        L.u[e >> 1] = __builtin_amdgcn_perm(f2u(v[e + 1] - t1), f2u(v[e] - t0), 0x07060302u);
    }
    hi = H.s; lo = L.s;
}

// A-fragment (split hi/lo) from fp32 LDS activations, row stride 68.
__device__ __forceinline__ void afrag_split(const float* act, int row, int kbase,
                                            s16x8& hi, s16x8& lo) {
    const float4 v0 = *(const float4*)(act + row * 68 + kbase);
    const float4 v1 = *(const float4*)(act + row * 68 + kbase + 4);
    const float v[8] = {v0.x, v0.y, v0.z, v0.w, v1.x, v1.y, v1.z, v1.w};
    splitpack8(v, hi, lo);
}

// 16x16 tile of act[32x64] @ W[64x64] from packed fragments (8-frag matrix).
__device__ __forceinline__ f32x4 node_tile_pk(const float* act, const s16x8* __restrict__ wb,
                                              int mt, int nt, int lane) {
    const int row = mt * 16 + (lane & 15);
    const int g   = lane >> 4;
    f32x4 acc = {0.f, 0.f, 0.f, 0.f};
    #pragma unroll
    for (int kg = 0; kg < 2; ++kg) {
        s16x8 ah, al;
        afrag_split(act, row, kg * 32 + g * 8, ah, al);
        const s16x8 bh = wb[(kg * 4 + nt) * 64 + lane];
        const s16x8 bl = wb[512 + (kg * 4 + nt) * 64 + lane];
        acc = MFMA(ah, bh, acc, 0, 0, 0);
        acc = MFMA(ah, bl, acc, 0, 0, 0);
        acc = MFMA(al, bh, acc, 0, 0, 0);
    }
    return acc;
}

// X1 pair-feature fragment: elu(A[f] + B[f] + d*wd[f]) for f = fbase..fbase+7
__device__ __forceinline__ void x1frag(const float* Arow, const float* Brow,
                                       const float* wdg, float d, int fbase,
                                       s16x8& hi, s16x8& lo) {
    const float4 a0 = *(const float4*)(Arow + fbase);
    const float4 a1 = *(const float4*)(Arow + fbase + 4);
    const float4 c0 = *(const float4*)(Brow + fbase);
    const float4 c1 = *(const float4*)(Brow + fbase + 4);
    const float4 w0 = *(const float4*)(wdg + fbase);
    const float4 w1 = *(const float4*)(wdg + fbase + 4);
    float v[8];
    v[0] = elu_f(fmaf(d, w0.x, a0.x + c0.x));
    v[1] = elu_f(fmaf(d, w0.y, a0.y + c0.y));
    v[2] = elu_f(fmaf(d, w0.z, a0.z + c0.z));
    v[3] = elu_f(fmaf(d, w0.w, a0.w + c0.w));
    v[4] = elu_f(fmaf(d, w1.x, a1.x + c1.x));
    v[5] = elu_f(fmaf(d, w1.y, a1.y + c1.y));
    v[6] = elu_f(fmaf(d, w1.z, a1.z + c1.z));
    v[7] = elu_f(fmaf(d, w1.w, a1.w + c1.w));
    splitpack8(v, hi, lo);
}

// ---------------- prep: pack weights into split-bf16 fragment planes ----------------
__device__ __forceinline__ short bfh_rn(float x) {
    union { float f; unsigned u; } c; c.f = x;
    return (short)((c.u + 0x7fffu + ((c.u >> 16) & 1u)) >> 16);
}
__device__ __forceinline__ void split_tr(float x, short& hi, short& lo) {
    union { float f; unsigned u; } c; c.f = x;
    hi = (short)(c.u >> 16);
    union { unsigned u; float f; } t; t.u = c.u & 0xffff0000u;
    lo = bfh_rn(x - t.f);
}

__global__ __launch_bounds__(64)
void prep_kernel(const float* __restrict__ We,  const float* __restrict__ Ws0,
                 const float* __restrict__ Ws1, const float* __restrict__ Wr0,
                 const float* __restrict__ Wa0, const float* __restrict__ Wa1,
                 const float* __restrict__ Wr1, const float* __restrict__ Wr2,
                 s16x8* __restrict__ ws)
{
    const int b = blockIdx.x, lane = threadIdx.x;
    const float* W; int nnt, nfrag, base, frag;
    if      (b < 8)   { W = We;  nnt = 4; nfrag = 8;  base = OFF_ENC; frag = b; }
    else if (b < 16)  { W = Ws0; nnt = 4; nfrag = 8;  base = OFF_S0;  frag = b - 8; }
    else if (b < 24)  { W = Ws1; nnt = 4; nfrag = 8;  base = OFF_S1;  frag = b - 16; }
    else if (b < 56)  { W = Wr0; nnt = 8; nfrag = 32; base = OFF_R0;  frag = b - 24; }
    else if (b < 88)  { W = Wa0; nnt = 8; nfrag = 32; base = OFF_A0;  frag = b - 56; }
    else if (b < 104) { W = Wa1; nnt = 4; nfrag = 16; base = OFF_A1;  frag = b - 88; }
    else if (b < 120) { W = Wr1; nnt = 4; nfrag = 16; base = OFF_R1;  frag = b - 104; }
    else              { W = Wr2; nnt = 4; nfrag = 8;  base = OFF_R2;  frag = b - 120; }
    const int kg = frag / nnt, nt = frag % nnt;
    const int N  = nnt * 16;
    const int g  = lane >> 4, col = nt * 16 + (lane & 15);
    s16x8 hi, lo;
    #pragma unroll
    for (int e = 0; e < 8; ++e) {
        short a, c; split_tr(W[(kg * 32 + g * 8 + e) * N + col], a, c);
        hi[e] = a; lo[e] = c;
    }
    ws[base + frag * 64 + lane]              = hi;
    ws[base + nfrag * 64 + frag * 64 + lane] = lo;
}

// ---------------- main ----------------
__global__ __launch_bounds__(NT, 1)
void gh_kernel(const float* __restrict__ S,
               const float* __restrict__ b_enc,
               const float* __restrict__ b_self0, const float* __restrict__ b_self1,
               const float* __restrict__ W_rel0,  const float* __restrict__ b_rel0,
               const float* __restrict__ b_rel1,  const float* __restrict__ b_rel2,
               const float* __restrict__ W_att0,  const float* __restrict__ b_att0,
               const float* __restrict__ b_att1,
               const float* __restrict__ W_att2,  const float* __restrict__ b_att2,
               const s16x8* __restrict__ wp,
               float* __restrict__ Out)
{
    // LDS: 3*8704 + 67584 + 2*32768 + 1024 + 128 + 1024 = 161,408 B (< 160 KiB)
    __shared__ __align__(16) float sbuf[32 * 68];    // s; later self_dyn
    __shared__ __align__(16) float encb[32 * 68];    // enc; later Ubuf/Rbuf
    __shared__ __align__(16) float hbuf[32 * 68];    // h; later Tbuf
    __shared__ __align__(16) float ABm[4][32 * 132]; // 0:Ar 1:Br 2:Aa 3:Ba
    __shared__ __align__(16) s16x8 wstpA[2048];      // packed W_att1
    __shared__ __align__(16) s16x8 wstpR[2048];      // packed W_rel1
    __shared__ float d2l[4 * 64];
    __shared__ float cntl[32];
    __shared__ float wdl[2][128];                    // dist rows: 0 rel, 1 att

    const int tid  = threadIdx.x;
    const int w    = tid >> 6;
    const int lane = tid & 63;
    const int g    = lane >> 4;
    const int b0   = blockIdx.x * NG;
    float* sd   = sbuf;
    float* Tb   = hbuf;
    float* Ubuf = encb;        // [4][68], alive after encb is dead
    float* Rbuf = encb + 512;  // [4][64]

    // ---- P0: load s, stage packed W_att1 + W_rel1, load dist rows ----
    {
        const float* src = S + (size_t)b0 * NN * NCL;
        for (int idx = tid; idx < 32 * 64; idx += NT)
            sbuf[(idx >> 6) * 68 + (idx & 63)] = src[idx];
        for (int idx = tid; idx < 2048; idx += NT) {
            wstpA[idx] = wp[OFF_A1 + idx];
            wstpR[idx] = wp[OFF_R1 + idx];
        }
        if (tid < 128) {
            wdl[0][tid] = W_rel0[128 * 128 + tid];
            wdl[1][tid] = W_att0[128 * 128 + tid];
        }
    }
    __syncthreads();

    if (tid < 256) {
        const int bi = tid >> 6, i = (tid >> 3) & 7, j = tid & 7;
        const float dx = sbuf[(bi * 8 + i) * 68 + 0] - sbuf[(bi * 8 + j) * 68 + 0];
        const float dy = sbuf[(bi * 8 + i) * 68 + 1] - sbuf[(bi * 8 + j) * 68 + 1];
        d2l[bi * 64 + i * 8 + j] = dx * dx + dy * dy;
    }

    // ---- P1: enc (waves 0-7) ----
    if (w < 8) {
        const int mt = w & 1, nt = w >> 1;
        f32x4 acc = node_tile_pk(sbuf, wp + OFF_ENC, mt, nt, lane);
        const int   col = nt * 16 + (lane & 15);
        const float be  = b_enc[col];
        #pragma unroll
        for (int reg = 0; reg < 4; ++reg) {
            const int row = mt * 16 + g * 4 + reg;
            float v = acc[reg] + be;
            if (col < 2) v = sbuf[row * 68 + col];
            encb[row * 68 + col] = v;
        }
    }
    __syncthreads();

    // ---- P2: h = elu(enc @ W_self0 + b) (waves 0-7) ----
    if (w < 8) {
        const int mt = w & 1, nt = w >> 1;
        f32x4 acc = node_tile_pk(encb, wp + OFF_S0, mt, nt, lane);
        const int   col = nt * 16 + (lane & 15);
        const float bs  = b_self0[col];
        #pragma unroll
        for (int reg = 0; reg < 4; ++reg)
            hbuf[(mt * 16 + g * 4 + reg) * 68 + col] = elu_f(acc[reg] + bs);
    }
    __syncthreads();

    // ---- P3: self1 (waves 0-7) + pair projections (all 16 waves) ----
    if (w < 8) {
        const int mt = w & 1, nt = w >> 1;
        f32x4 acc = node_tile_pk(hbuf, wp + OFF_S1, mt, nt, lane);
        const int   col = nt * 16 + (lane & 15);
        const float bs  = b_self1[col];
        #pragma unroll
        for (int reg = 0; reg < 4; ++reg) {
            const int row = mt * 16 + g * 4 + reg;
            sd[row * 68 + col] = acc[reg] + bs + hbuf[row * 68 + col];
        }
    }
    {
        const int mtp = w >> 3, ntp = w & 7;
        const int row = mtp * 16 + (lane & 15);
        const int col = ntp * 16 + (lane & 15);
        s16x8 eh[2], el[2];
        afrag_split(encb, row, g * 8, eh[0], el[0]);
        afrag_split(encb, row, 32 + g * 8, eh[1], el[1]);
        #pragma unroll
        for (int m = 0; m < 4; ++m) {
            const s16x8* wb = wp + ((m < 2) ? OFF_R0 : OFF_A0);
            const int kgo = (m & 1) * 2;
            f32x4 acc = {0.f, 0.f, 0.f, 0.f};
            #pragma unroll
            for (int kg = 0; kg < 2; ++kg) {
                const s16x8 bh = wb[((kgo + kg) * 8 + ntp) * 64 + lane];
                const s16x8 bl = wb[2048 + ((kgo + kg) * 8 + ntp) * 64 + lane];
                acc = MFMA(eh[kg], bh, acc, 0, 0, 0);
                acc = MFMA(eh[kg], bl, acc, 0, 0, 0);
                acc = MFMA(el[kg], bh, acc, 0, 0, 0);
            }
            const float badd = (m == 0) ? b_rel0[col] : (m == 2) ? b_att0[col] : 0.f;
            #pragma unroll
            for (int reg = 0; reg < 4; ++reg)
                ABm[m][(mtp * 16 + g * 4 + reg) * 132 + col] = acc[reg] + badd;
        }
    }
    __syncthreads();

    // ---- P4: merged att + rel pair pass (no intervening barrier) ----
    const int bi    = w >> 2;
    const int ihalf = (w >> 1) & 1;
    const int mt    = w & 1;
    const int pp    = (lane & 15) + 16 * mt;
    const int il    = pp >> 3, jj8 = pp & 7;
    const float* Arow_a = &ABm[2][(bi * 8 + ihalf * 4 + il) * 132];
    const float* Brow_a = &ABm[3][(bi * 8 + jj8) * 132];
    const float* Arow_r = &ABm[0][(bi * 8 + ihalf * 4 + il) * 132];
    const float* Brow_r = &ABm[1][(bi * 8 + jj8) * 132];
    const float dpair   = d2l[bi * 64 + (ihalf * 4 + il) * 8 + jj8];

    float attreg[4];
    {   // attention half
        const float ba2 = b_att2[0];
        float wa2v[4];
        f32x4 acc[4];
        #pragma unroll
        for (int nt = 0; nt < 4; ++nt) {
            wa2v[nt] = W_att2[nt * 16 + (lane & 15)];
            const float b1 = b_att1[nt * 16 + (lane & 15)];
            acc[nt] = {b1, b1, b1, b1};
        }
        #pragma unroll
        for (int kg = 0; kg < 4; ++kg) {   // kg-outer: one frag pair live at a time
            s16x8 ah, al;
            x1frag(Arow_a, Brow_a, &wdl[1][0], dpair, kg * 32 + g * 8, ah, al);
            #pragma unroll
            for (int nt = 0; nt < 4; ++nt) {
                const s16x8 bh = wstpA[(kg * 4 + nt) * 64 + lane];
                const s16x8 bl = wstpA[1024 + (kg * 4 + nt) * 64 + lane];
                acc[nt] = MFMA(ah, bh, acc[nt], 0, 0, 0);
                acc[nt] = MFMA(ah, bl, acc[nt], 0, 0, 0);
                acc[nt] = MFMA(al, bh, acc[nt], 0, 0, 0);
            }
        }
        #pragma unroll
        for (int reg = 0; reg < 4; ++reg) {
            float s = 0.f;
            #pragma unroll
            for (int nt = 0; nt < 4; ++nt) s += elu_f(acc[nt][reg]) * wa2v[nt];
            s += __shfl_xor(s, 1, 64);
            s += __shfl_xor(s, 2, 64);
            s += __shfl_xor(s, 4, 64);
            s += __shfl_xor(s, 8, 64);
            attreg[reg] = 1.f / (1.f + __expf(-(s + ba2)));
        }
    }
    {   // rel half
        f32x4 acc[4];
        #pragma unroll
        for (int nt = 0; nt < 4; ++nt) {
            const float b1 = b_rel1[nt * 16 + (lane & 15)];
            acc[nt] = {b1, b1, b1, b1};
        }
        #pragma unroll
        for (int kg = 0; kg < 4; ++kg) {
            s16x8 ah, al;
            x1frag(Arow_r, Brow_r, &wdl[0][0], dpair, kg * 32 + g * 8, ah, al);
            #pragma unroll
            for (int nt = 0; nt < 4; ++nt) {
                const s16x8 bh = wstpR[(kg * 4 + nt) * 64 + lane];
                const s16x8 bl = wstpR[1024 + (kg * 4 + nt) * 64 + lane];
                acc[nt] = MFMA(ah, bh, acc[nt], 0, 0, 0);
                acc[nt] = MFMA(ah, bl, acc[nt], 0, 0, 0);
                acc[nt] = MFMA(al, bh, acc[nt], 0, 0, 0);
            }
        }
        // masked-attention coefficients; rows owned by (g, reg)
        const int ifull = ihalf * 4 + 2 * mt + (g >> 1);
        float coef[4], cpart = 0.f;
        #pragma unroll
        for (int reg = 0; reg < 4; ++reg) {
            const int jj = 4 * (g & 1) + reg;
            coef[reg] = (jj == ifull) ? 0.f : attreg[reg];
            cpart += coef[reg];
        }
        const float csum = cpart + __shfl_xor(cpart, 16, 64);
        if (((g & 1) == 0) && ((lane & 15) == 0))
            cntl[bi * 8 + ifull] = csum;
        #pragma unroll
        for (int nt = 0; nt < 4; ++nt) {
            float tpart = 0.f;
            #pragma unroll
            for (int reg = 0; reg < 4; ++reg)
                tpart += coef[reg] * elu_f(acc[nt][reg]);
            const float tsum = tpart + __shfl_xor(tpart, 16, 64);
            if ((g & 1) == 0)
                Tb[(bi * 8 + ifull) * 68 + nt * 16 + (lane & 15)] = tsum;
        }
    }
    __syncthreads();

    // ---- P5: U[b] = sum_i T[i] (into dead encb region) ----
    if (tid < 256) {
        const int b = tid >> 6, c = tid & 63;
        float u = 0.f;
        #pragma unroll
        for (int i = 0; i < 8; ++i) u += Tb[(b * 8 + i) * 68 + c];
        Ubuf[b * 68 + c] = u;
    }
    __syncthreads();

    // ---- P6: R = U4 @ W_rel2 via MFMA (waves 0-3) ----
    if (w < 4) {
        const int nt2 = w;
        f32x4 acc = {0.f, 0.f, 0.f, 0.f};
        const int row = lane & 15;
        #pragma unroll
        for (int kg = 0; kg < 2; ++kg) {
            float4 q0 = {0.f, 0.f, 0.f, 0.f}, q1 = {0.f, 0.f, 0.f, 0.f};
            if (row < 4) {
                q0 = *(const float4*)(Ubuf + row * 68 + kg * 32 + g * 8);
                q1 = *(const float4*)(Ubuf + row * 68 + kg * 32 + g * 8 + 4);
            }
            const float v[8] = {q0.x, q0.y, q0.z, q0.w, q1.x, q1.y, q1.z, q1.w};
            s16x8 uh, ul;
            splitpack8(v, uh, ul);
            const s16x8 bh = wp[OFF_R2 + (kg * 4 + nt2) * 64 + lane];
            const s16x8 bl = wp[OFF_R2 + 512 + (kg * 4 + nt2) * 64 + lane];
            acc = MFMA(uh, bh, acc, 0, 0, 0);
            acc = MFMA(uh, bl, acc, 0, 0, 0);
            acc = MFMA(ul, bh, acc, 0, 0, 0);
        }
        if (g == 0) {
            #pragma unroll
            for (int reg = 0; reg < 4; ++reg)
                Rbuf[reg * 64 + nt2 * 16 + (lane & 15)] = acc[reg];
        }
    }
    __syncthreads();

    // ---- P7: Out = sum_i sd + R + C*b_rel2 + U ----
    if (tid < 256) {
        const int b = tid >> 6, c = tid & 63;
        float sds = 0.f, C = 0.f;
        #pragma unroll
        for (int i = 0; i < 8; ++i) {
            sds += sd[(b * 8 + i) * 68 + c];
            C   += cntl[b * 8 + i];
        }
        Out[(size_t)(b0 + b) * 64 + c] = sds + Rbuf[b * 64 + c] + C * b_rel2[c] + Ubuf[b * 68 + c];
    }
}

extern "C" void kernel_launch(void* const* d_in, const int* in_sizes, int n_in,
                              void* d_out, int out_size, void* d_ws, size_t ws_size,
                              hipStream_t stream) {
    const float* S       = (const float*)d_in[0];
    const float* W_enc   = (const float*)d_in[1];
    const float* b_enc   = (const float*)d_in[2];
    const float* W_self0 = (const float*)d_in[3];
    const float* b_self0 = (const float*)d_in[4];
    const float* W_self1 = (const float*)d_in[5];
    const float* b_self1 = (const float*)d_in[6];
    const float* W_rel0  = (const float*)d_in[7];
    const float* b_rel0  = (const float*)d_in[8];
    const float* W_rel1  = (const float*)d_in[9];
    const float* b_rel1  = (const float*)d_in[10];
    const float* W_rel2  = (const float*)d_in[11];
    const float* b_rel2  = (const float*)d_in[12];
    const float* W_att0  = (const float*)d_in[13];
    const float* b_att0  = (const float*)d_in[14];
    const float* W_att1  = (const float*)d_in[15];
    const float* b_att1  = (const float*)d_in[16];
    const float* W_att2  = (const float*)d_in[17];
    const float* b_att2  = (const float*)d_in[18];

    s16x8* wpk = (s16x8*)d_ws;

    prep_kernel<<<dim3(128), dim3(64), 0, stream>>>(
        W_enc, W_self0, W_self1, W_rel0, W_att0, W_att1, W_rel1, W_rel2, wpk);

    const int nB   = in_sizes[0] / (NN * NCL);   // 8192
    const int grid = nB / NG;                    // 2048

    gh_kernel<<<dim3(grid), dim3(NT), 0, stream>>>(
        S, b_enc, b_self0, b_self1,
        W_rel0, b_rel0, b_rel1, b_rel2,
        W_att0, b_att0, b_att1, W_att2, b_att2,
        wpk, (float*)d_out);
}

// Round 6
// 208.962 us; speedup vs baseline: 25.9302x; 1.0698x over previous
//
#include <hip/hip_runtime.h>
#include <math.h>

constexpr int NCL = 64;
constexpr int NN  = 8;
constexpr int NG  = 2;      // batch elems per block
constexpr int NT  = 512;    // 8 waves

typedef __attribute__((ext_vector_type(4))) float f32x4;
typedef __attribute__((ext_vector_type(8))) short s16x8;
#define MFMA __builtin_amdgcn_mfma_f32_16x16x32_bf16

// workspace layout offsets (units of s16x8 = 16 B)
constexpr int OFF_ENC = 0;      // 8 frags  (hi 512 | lo 512)
constexpr int OFF_S0  = 1024;
constexpr int OFF_S1  = 2048;
constexpr int OFF_R0  = 3072;   // 32 frags (hi 2048 | lo 2048)
constexpr int OFF_A0  = 7168;
constexpr int OFF_A1  = 11264;  // 16 frags (hi 1024 | lo 1024)
constexpr int OFF_R1  = 13312;
constexpr int OFF_R2  = 15360;  // 8 frags  (hi 512 | lo 512)

__device__ __forceinline__ float elu_f(float x) { return x > 0.f ? x : __expf(x) - 1.f; }

__device__ __forceinline__ unsigned f2u(float x) { union { float f; unsigned u; } c; c.f = x; return c.u; }
__device__ __forceinline__ float u2f(unsigned u) { union { unsigned u; float f; } c; c.u = u; return c.f; }

// Pack 8 fp32 -> bf16 hi (truncated) + bf16 lo (truncated residual) fragments.
__device__ __forceinline__ void splitpack8(const float v[8], s16x8& hi, s16x8& lo) {
    union { s16x8 s; unsigned u[4]; } H, L;
    #pragma unroll
    for (int e = 0; e < 8; e += 2) {
        H.u[e >> 1] = __builtin_amdgcn_perm(f2u(v[e + 1]), f2u(v[e]), 0x07060302u);
        const float t0 = u2f(f2u(v[e])     & 0xffff0000u);
        const float t1 = u2f(f2u(v[e + 1]) & 0xffff0000u);
        L.u[e >> 1] = __builtin_amdgcn_perm(f2u(v[e + 1] - t1), f2u(v[e] - t0), 0x07060302u);
    }
    hi = H.s; lo = L.s;
}

// A-fragment (split hi/lo) from fp32 LDS activations, row stride 68.
__device__ __forceinline__ void afrag_split(const float* act, int row, int kbase,
                                            s16x8& hi, s16x8& lo) {
    const float4 v0 = *(const float4*)(act + row * 68 + kbase);
    const float4 v1 = *(const float4*)(act + row * 68 + kbase + 4);
    const float v[8] = {v0.x, v0.y, v0.z, v0.w, v1.x, v1.y, v1.z, v1.w};
    splitpack8(v, hi, lo);
}

// 16x16 tile of act[16x64] @ W[64x64] from packed fragments (8-frag matrix).
__device__ __forceinline__ f32x4 node_tile_pk(const float* act, const s16x8* __restrict__ wb,
                                              int mt, int nt, int lane) {
    const int row = mt * 16 + (lane & 15);
    const int g   = lane >> 4;
    f32x4 acc = {0.f, 0.f, 0.f, 0.f};
    #pragma unroll
    for (int kg = 0; kg < 2; ++kg) {
        s16x8 ah, al;
        afrag_split(act, row, kg * 32 + g * 8, ah, al);
        const s16x8 bh = wb[(kg * 4 + nt) * 64 + lane];
        const s16x8 bl = wb[512 + (kg * 4 + nt) * 64 + lane];
        acc = MFMA(ah, bh, acc, 0, 0, 0);
        acc = MFMA(ah, bl, acc, 0, 0, 0);
        acc = MFMA(al, bh, acc, 0, 0, 0);
    }
    return acc;
}

// X1 pair-feature fragment: elu(A[f] + B[f] + d*wd[f]) for f = fbase..fbase+7
__device__ __forceinline__ void x1frag(const float* Arow, const float* Brow,
                                       const float* wdg, float d, int fbase,
                                       s16x8& hi, s16x8& lo) {
    const float4 a0 = *(const float4*)(Arow + fbase);
    const float4 a1 = *(const float4*)(Arow + fbase + 4);
    const float4 c0 = *(const float4*)(Brow + fbase);
    const float4 c1 = *(const float4*)(Brow + fbase + 4);
    const float4 w0 = *(const float4*)(wdg + fbase);
    const float4 w1 = *(const float4*)(wdg + fbase + 4);
    float v[8];
    v[0] = elu_f(fmaf(d, w0.x, a0.x + c0.x));
    v[1] = elu_f(fmaf(d, w0.y, a0.y + c0.y));
    v[2] = elu_f(fmaf(d, w0.z, a0.z + c0.z));
    v[3] = elu_f(fmaf(d, w0.w, a0.w + c0.w));
    v[4] = elu_f(fmaf(d, w1.x, a1.x + c1.x));
    v[5] = elu_f(fmaf(d, w1.y, a1.y + c1.y));
    v[6] = elu_f(fmaf(d, w1.z, a1.z + c1.z));
    v[7] = elu_f(fmaf(d, w1.w, a1.w + c1.w));
    splitpack8(v, hi, lo);
}

// ---------------- prep: pack weights into split-bf16 fragment planes ----------------
__device__ __forceinline__ short bfh_rn(float x) {
    union { float f; unsigned u; } c; c.f = x;
    return (short)((c.u + 0x7fffu + ((c.u >> 16) & 1u)) >> 16);
}
__device__ __forceinline__ void split_tr(float x, short& hi, short& lo) {
    union { float f; unsigned u; } c; c.f = x;
    hi = (short)(c.u >> 16);
    union { unsigned u; float f; } t; t.u = c.u & 0xffff0000u;
    lo = bfh_rn(x - t.f);
}

__global__ __launch_bounds__(64)
void prep_kernel(const float* __restrict__ We,  const float* __restrict__ Ws0,
                 const float* __restrict__ Ws1, const float* __restrict__ Wr0,
                 const float* __restrict__ Wa0, const float* __restrict__ Wa1,
                 const float* __restrict__ Wr1, const float* __restrict__ Wr2,
                 s16x8* __restrict__ ws)
{
    const int b = blockIdx.x, lane = threadIdx.x;
    const float* W; int nnt, nfrag, base, frag;
    if      (b < 8)   { W = We;  nnt = 4; nfrag = 8;  base = OFF_ENC; frag = b; }
    else if (b < 16)  { W = Ws0; nnt = 4; nfrag = 8;  base = OFF_S0;  frag = b - 8; }
    else if (b < 24)  { W = Ws1; nnt = 4; nfrag = 8;  base = OFF_S1;  frag = b - 16; }
    else if (b < 56)  { W = Wr0; nnt = 8; nfrag = 32; base = OFF_R0;  frag = b - 24; }
    else if (b < 88)  { W = Wa0; nnt = 8; nfrag = 32; base = OFF_A0;  frag = b - 56; }
    else if (b < 104) { W = Wa1; nnt = 4; nfrag = 16; base = OFF_A1;  frag = b - 88; }
    else if (b < 120) { W = Wr1; nnt = 4; nfrag = 16; base = OFF_R1;  frag = b - 104; }
    else              { W = Wr2; nnt = 4; nfrag = 8;  base = OFF_R2;  frag = b - 120; }
    const int kg = frag / nnt, nt = frag % nnt;
    const int N  = nnt * 16;
    const int g  = lane >> 4, col = nt * 16 + (lane & 15);
    s16x8 hi, lo;
    #pragma unroll
    for (int e = 0; e < 8; ++e) {
        short a, c; split_tr(W[(kg * 32 + g * 8 + e) * N + col], a, c);
        hi[e] = a; lo[e] = c;
    }
    ws[base + frag * 64 + lane]              = hi;
    ws[base + nfrag * 64 + frag * 64 + lane] = lo;
}

// ---------------- main ----------------
__global__ __launch_bounds__(NT, 6)
void gh_kernel(const float* __restrict__ S,
               const float* __restrict__ b_enc,
               const float* __restrict__ b_self0, const float* __restrict__ b_self1,
               const float* __restrict__ W_rel0,  const float* __restrict__ b_rel0,
               const float* __restrict__ b_rel1,  const float* __restrict__ b_rel2,
               const float* __restrict__ W_att0,  const float* __restrict__ b_att0,
               const float* __restrict__ b_att1,
               const float* __restrict__ W_att2,  const float* __restrict__ b_att2,
               const s16x8* __restrict__ wp,
               float* __restrict__ Out)
{
    // LDS: 3*4352 + 33792 + 512 + 64 + 1024 = 48,448 B  -> 3 blocks/CU
    __shared__ __align__(16) float sbuf[16 * 68];    // s; later self_dyn
    __shared__ __align__(16) float encb[16 * 68];    // enc; later Ubuf/Rbuf
    __shared__ __align__(16) float hbuf[16 * 68];    // h; later Tbuf
    __shared__ __align__(16) float ABm[4][16 * 132]; // 0:Ar 1:Br 2:Aa 3:Ba
    __shared__ float d2l[2 * 64];
    __shared__ float cntl[16];
    __shared__ float wdl[2][128];                    // dist rows: 0 rel, 1 att

    const int tid  = threadIdx.x;
    const int w    = tid >> 6;
    const int lane = tid & 63;
    const int g    = lane >> 4;
    const int b0   = blockIdx.x * NG;
    float* sd   = sbuf;
    float* Tb   = hbuf;
    float* Ubuf = encb;        // [2][68], alive after encb is dead
    float* Rbuf = encb + 512;  // [2][64]

    // ---- P0: load s, dist rows ----
    {
        const float* src = S + (size_t)b0 * NN * NCL;
        for (int idx = tid; idx < 16 * 64; idx += NT)
            sbuf[(idx >> 6) * 68 + (idx & 63)] = src[idx];
        if (tid < 128) {
            wdl[0][tid] = W_rel0[128 * 128 + tid];
            wdl[1][tid] = W_att0[128 * 128 + tid];
        }
    }
    __syncthreads();

    if (tid < 128) {
        const int bi = tid >> 6, i = (tid >> 3) & 7, j = tid & 7;
        const float dx = sbuf[(bi * 8 + i) * 68 + 0] - sbuf[(bi * 8 + j) * 68 + 0];
        const float dy = sbuf[(bi * 8 + i) * 68 + 1] - sbuf[(bi * 8 + j) * 68 + 1];
        d2l[bi * 64 + i * 8 + j] = dx * dx + dy * dy;
    }

    // ---- P1: enc (waves 0-3) ----
    if (w < 4) {
        const int nt = w;
        f32x4 acc = node_tile_pk(sbuf, wp + OFF_ENC, 0, nt, lane);
        const int   col = nt * 16 + (lane & 15);
        const float be  = b_enc[col];
        #pragma unroll
        for (int reg = 0; reg < 4; ++reg) {
            const int row = g * 4 + reg;
            float v = acc[reg] + be;
            if (col < 2) v = sbuf[row * 68 + col];
            encb[row * 68 + col] = v;
        }
    }
    __syncthreads();

    // ---- P2: h = elu(enc @ W_self0 + b) (waves 0-3) ----
    if (w < 4) {
        const int nt = w;
        f32x4 acc = node_tile_pk(encb, wp + OFF_S0, 0, nt, lane);
        const int   col = nt * 16 + (lane & 15);
        const float bs  = b_self0[col];
        #pragma unroll
        for (int reg = 0; reg < 4; ++reg)
            hbuf[(g * 4 + reg) * 68 + col] = elu_f(acc[reg] + bs);
    }
    __syncthreads();

    // ---- P3: self1 (waves 0-3) + pair projections (all 8 waves) ----
    if (w < 4) {
        const int nt = w;
        f32x4 acc = node_tile_pk(hbuf, wp + OFF_S1, 0, nt, lane);
        const int   col = nt * 16 + (lane & 15);
        const float bs  = b_self1[col];
        #pragma unroll
        for (int reg = 0; reg < 4; ++reg) {
            const int row = g * 4 + reg;
            sd[row * 68 + col] = acc[reg] + bs + hbuf[row * 68 + col];
        }
    }
    {
        const int ntp = w;                       // 8 column tiles
        const int row = lane & 15;
        const int col = ntp * 16 + (lane & 15);
        s16x8 eh[2], el[2];
        afrag_split(encb, row, g * 8, eh[0], el[0]);
        afrag_split(encb, row, 32 + g * 8, eh[1], el[1]);
        #pragma unroll
        for (int m = 0; m < 4; ++m) {
            const s16x8* wb = wp + ((m < 2) ? OFF_R0 : OFF_A0);
            const int kgo = (m & 1) * 2;
            f32x4 acc = {0.f, 0.f, 0.f, 0.f};
            #pragma unroll
            for (int kg = 0; kg < 2; ++kg) {
                const s16x8 bh = wb[((kgo + kg) * 8 + ntp) * 64 + lane];
                const s16x8 bl = wb[2048 + ((kgo + kg) * 8 + ntp) * 64 + lane];
                acc = MFMA(eh[kg], bh, acc, 0, 0, 0);
                acc = MFMA(eh[kg], bl, acc, 0, 0, 0);
                acc = MFMA(el[kg], bh, acc, 0, 0, 0);
            }
            const float badd = (m == 0) ? b_rel0[col] : (m == 2) ? b_att0[col] : 0.f;
            #pragma unroll
            for (int reg = 0; reg < 4; ++reg)
                ABm[m][(g * 4 + reg) * 132 + col] = acc[reg] + badd;
        }
    }
    __syncthreads();

    // ---- P4: merged att + rel pair pass ----
    const int bi    = w >> 2;
    const int ihalf = (w >> 1) & 1;
    const int mt    = w & 1;
    const int pp    = (lane & 15) + 16 * mt;
    const int il    = pp >> 3, jj8 = pp & 7;
    const float* Arow_a = &ABm[2][(bi * 8 + ihalf * 4 + il) * 132];
    const float* Brow_a = &ABm[3][(bi * 8 + jj8) * 132];
    const float* Arow_r = &ABm[0][(bi * 8 + ihalf * 4 + il) * 132];
    const float* Brow_r = &ABm[1][(bi * 8 + jj8) * 132];
    const float dpair   = d2l[bi * 64 + (ihalf * 4 + il) * 8 + jj8];

    float attreg[4];
    {   // attention half
        const float ba2 = b_att2[0];
        float wa2v[4];
        f32x4 acc[4];
        #pragma unroll
        for (int nt = 0; nt < 4; ++nt) {
            wa2v[nt] = W_att2[nt * 16 + (lane & 15)];
            const float b1 = b_att1[nt * 16 + (lane & 15)];
            acc[nt] = {b1, b1, b1, b1};
        }
        #pragma unroll
        for (int kg = 0; kg < 4; ++kg) {
            s16x8 ah, al;
            x1frag(Arow_a, Brow_a, &wdl[1][0], dpair, kg * 32 + g * 8, ah, al);
            #pragma unroll
            for (int nt = 0; nt < 4; ++nt) {
                const s16x8 bh = wp[OFF_A1 + (kg * 4 + nt) * 64 + lane];
                const s16x8 bl = wp[OFF_A1 + 1024 + (kg * 4 + nt) * 64 + lane];
                acc[nt] = MFMA(ah, bh, acc[nt], 0, 0, 0);
                acc[nt] = MFMA(ah, bl, acc[nt], 0, 0, 0);
                acc[nt] = MFMA(al, bh, acc[nt], 0, 0, 0);
            }
        }
        #pragma unroll
        for (int reg = 0; reg < 4; ++reg) {
            float s = 0.f;
            #pragma unroll
            for (int nt = 0; nt < 4; ++nt) s += elu_f(acc[nt][reg]) * wa2v[nt];
            s += __shfl_xor(s, 1, 64);
            s += __shfl_xor(s, 2, 64);
            s += __shfl_xor(s, 4, 64);
            s += __shfl_xor(s, 8, 64);
            attreg[reg] = 1.f / (1.f + __expf(-(s + ba2)));
        }
    }
    {   // rel half
        f32x4 acc[4];
        #pragma unroll
        for (int nt = 0; nt < 4; ++nt) {
            const float b1 = b_rel1[nt * 16 + (lane & 15)];
            acc[nt] = {b1, b1, b1, b1};
        }
        #pragma unroll
        for (int kg = 0; kg < 4; ++kg) {
            s16x8 ah, al;
            x1frag(Arow_r, Brow_r, &wdl[0][0], dpair, kg * 32 + g * 8, ah, al);
            #pragma unroll
            for (int nt = 0; nt < 4; ++nt) {
                const s16x8 bh = wp[OFF_R1 + (kg * 4 + nt) * 64 + lane];
                const s16x8 bl = wp[OFF_R1 + 1024 + (kg * 4 + nt) * 64 + lane];
                acc[nt] = MFMA(ah, bh, acc[nt], 0, 0, 0);
                acc[nt] = MFMA(ah, bl, acc[nt], 0, 0, 0);
                acc[nt] = MFMA(al, bh, acc[nt], 0, 0, 0);
            }
        }
        // masked-attention coefficients; rows owned by (g, reg)
        const int ifull = ihalf * 4 + 2 * mt + (g >> 1);
        float coef[4], cpart = 0.f;
        #pragma unroll
        for (int reg = 0; reg < 4; ++reg) {
            const int jj = 4 * (g & 1) + reg;
            coef[reg] = (jj == ifull) ? 0.f : attreg[reg];
            cpart += coef[reg];
        }
        const float csum = cpart + __shfl_xor(cpart, 16, 64);
        if (((g & 1) == 0) && ((lane & 15) == 0))
            cntl[bi * 8 + ifull] = csum;
        #pragma unroll
        for (int nt = 0; nt < 4; ++nt) {
            float tpart = 0.f;
            #pragma unroll
            for (int reg = 0; reg < 4; ++reg)
                tpart += coef[reg] * elu_f(acc[nt][reg]);
            const float tsum = tpart + __shfl_xor(tpart, 16, 64);
            if ((g & 1) == 0)
                Tb[(bi * 8 + ifull) * 68 + nt * 16 + (lane & 15)] = tsum;
        }
    }
    __syncthreads();

    // ---- P5: U[b] = sum_i T[i] (into dead encb region) ----
    if (tid < 128) {
        const int b = tid >> 6, c = tid & 63;
        float u = 0.f;
        #pragma unroll
        for (int i = 0; i < 8; ++i) u += Tb[(b * 8 + i) * 68 + c];
        Ubuf[b * 68 + c] = u;
    }
    __syncthreads();

    // ---- P6: R = U2 @ W_rel2 via MFMA (waves 0-3) ----
    if (w < 4) {
        const int nt2 = w;
        f32x4 acc = {0.f, 0.f, 0.f, 0.f};
        const int row = lane & 15;
        #pragma unroll
        for (int kg = 0; kg < 2; ++kg) {
            float4 q0 = {0.f, 0.f, 0.f, 0.f}, q1 = {0.f, 0.f, 0.f, 0.f};
            if (row < 2) {
                q0 = *(const float4*)(Ubuf + row * 68 + kg * 32 + g * 8);
                q1 = *(const float4*)(Ubuf + row * 68 + kg * 32 + g * 8 + 4);
            }
            const float v[8] = {q0.x, q0.y, q0.z, q0.w, q1.x, q1.y, q1.z, q1.w};
            s16x8 uh, ul;
            splitpack8(v, uh, ul);
            const s16x8 bh = wp[OFF_R2 + (kg * 4 + nt2) * 64 + lane];
            const s16x8 bl = wp[OFF_R2 + 512 + (kg * 4 + nt2) * 64 + lane];
            acc = MFMA(uh, bh, acc, 0, 0, 0);
            acc = MFMA(uh, bl, acc, 0, 0, 0);
            acc = MFMA(ul, bh, acc, 0, 0, 0);
        }
        if (g == 0) {
            #pragma unroll
            for (int reg = 0; reg < 2; ++reg)
                Rbuf[reg * 64 + nt2 * 16 + (lane & 15)] = acc[reg];
        }
    }
    __syncthreads();

    // ---- P7: Out = sum_i sd + R + C*b_rel2 + U ----
    if (tid < 128) {
        const int b = tid >> 6, c = tid & 63;
        float sds = 0.f, C = 0.f;
        #pragma unroll
        for (int i = 0; i < 8; ++i) {
            sds += sd[(b * 8 + i) * 68 + c];
            C   += cntl[b * 8 + i];
        }
        Out[(size_t)(b0 + b) * 64 + c] = sds + Rbuf[b * 64 + c] + C * b_rel2[c] + Ubuf[b * 68 + c];
    }
}

extern "C" void kernel_launch(void* const* d_in, const int* in_sizes, int n_in,
                              void* d_out, int out_size, void* d_ws, size_t ws_size,
                              hipStream_t stream) {
    const float* S       = (const float*)d_in[0];
    const float* W_enc   = (const float*)d_in[1];
    const float* b_enc   = (const float*)d_in[2];
    const float* W_self0 = (const float*)d_in[3];
    const float* b_self0 = (const float*)d_in[4];
    const float* W_self1 = (const float*)d_in[5];
    const float* b_self1 = (const float*)d_in[6];
    const float* W_rel0  = (const float*)d_in[7];
    const float* b_rel0  = (const float*)d_in[8];
    const float* W_rel1  = (const float*)d_in[9];
    const float* b_rel1  = (const float*)d_in[10];
    const float* W_rel2  = (const float*)d_in[11];
    const float* b_rel2  = (const float*)d_in[12];
    const float* W_att0  = (const float*)d_in[13];
    const float* b_att0  = (const float*)d_in[14];
    const float* W_att1  = (const float*)d_in[15];
    const float* b_att1  = (const float*)d_in[16];
    const float* W_att2  = (const float*)d_in[17];
    const float* b_att2  = (const float*)d_in[18];

    s16x8* wpk = (s16x8*)d_ws;

    prep_kernel<<<dim3(128), dim3(64), 0, stream>>>(
        W_enc, W_self0, W_self1, W_rel0, W_att0, W_att1, W_rel1, W_rel2, wpk);

    const int nB   = in_sizes[0] / (NN * NCL);   // 8192
    const int grid = nB / NG;                    // 4096

    gh_kernel<<<dim3(grid), dim3(NT), 0, stream>>>(
        S, b_enc, b_self0, b_self1,
        W_rel0, b_rel0, b_rel1, b_rel2,
        W_att0, b_att0, b_att1, W_att2, b_att2,
        wpk, (float*)d_out);
}